// Round 11
// baseline (1300.232 us; speedup 1.0000x reference)
//
#include <hip/hip_runtime.h>
#include <math.h>

// Problem constants (match reference)
#define NTOT  24576      // B*N nodes
#define NB    8
#define NPB   3072       // nodes per batch
#define HD    64
#define KNN   20
#define NTILE 24         // NPB/128

__device__ __forceinline__ float elu_f(float x){ return x > 0.f ? x : expm1f(x); }

// ---------------- encoder: x(NT,8) -> elu(elu(x@W1+b1)@W2+b2) (NT,64) + sq ----------------
__global__ __launch_bounds__(256) void enc_kernel(const float* __restrict__ x,
    const float* __restrict__ W1, const float* __restrict__ b1,
    const float* __restrict__ W2, const float* __restrict__ b2,
    float* __restrict__ out, float* __restrict__ sqo){
  __shared__ float sW1[256], sb1[32], sW2[2048], sb2[64];
  int t = threadIdx.x;
  if (t < 256) sW1[t] = W1[t];
  for (int i = t; i < 2048; i += 256) sW2[i] = W2[i];
  if (t < 32) sb1[t] = b1[t];
  if (t < 64) sb2[t] = b2[t];
  __syncthreads();
  int n = blockIdx.x*256 + t;
  const float4* xp = (const float4*)(x + (size_t)n*8);
  float4 x0 = xp[0], x1 = xp[1];
  float xi[8] = {x0.x,x0.y,x0.z,x0.w,x1.x,x1.y,x1.z,x1.w};
  float h1[32];
  #pragma unroll
  for (int j = 0; j < 32; j++){
    float a = sb1[j];
    #pragma unroll
    for (int d = 0; d < 8; d++) a = fmaf(xi[d], sW1[d*32+j], a);
    h1[j] = elu_f(a);
  }
  float4* op = (float4*)(out + (size_t)n*64);
  float ssum = 0.f;
  #pragma unroll
  for (int c4 = 0; c4 < 16; c4++){
    float a0 = sb2[c4*4+0], a1 = sb2[c4*4+1], a2 = sb2[c4*4+2], a3 = sb2[c4*4+3];
    #pragma unroll
    for (int d = 0; d < 32; d++){
      float hd = h1[d];
      float4 wv = *(const float4*)&sW2[d*64 + c4*4];
      a0 = fmaf(hd, wv.x, a0); a1 = fmaf(hd, wv.y, a1);
      a2 = fmaf(hd, wv.z, a2); a3 = fmaf(hd, wv.w, a3);
    }
    float4 o; o.x=elu_f(a0); o.y=elu_f(a1); o.z=elu_f(a2); o.w=elu_f(a3);
    ssum = fmaf(o.x,o.x,ssum); ssum = fmaf(o.y,o.y,ssum);
    ssum = fmaf(o.z,o.z,ssum); ssum = fmaf(o.w,o.w,ssum);
    op[c4] = o;
  }
  sqo[n] = ssum;
}

// ---------------- fused distance GEMM + per-32-group top-2 (K-split depth 16) ----------------
// grid = dim3(24, 24, NB). Block: 128q x 128c tile, 8x8 acc per thread.
// Summaries: per (row, 32-cand group) the 2 smallest values + local idx.
// Per row: branchless top-2 insert over the thread's 8 cands, then 2-level
// shfl_xor(1,2) sorted-2 merge across the 4 lanes of the group.
__global__ __launch_bounds__(256) void disttop_kernel(const float* __restrict__ feat,
    const float* __restrict__ sqn, float* __restrict__ topv, unsigned char* __restrict__ topi){
  __shared__ float As[16][128];
  __shared__ float Bs[16][128];
  int b  = blockIdx.z;
  int m0 = blockIdx.x * 128;
  int q0 = blockIdx.y * 128;
  const float* fb = feat + (size_t)b*NPB*HD;
  int t = threadIdx.x;
  int tx = t & 15, ty = t >> 4;
  float acc[8][8];
  #pragma unroll
  for (int i = 0; i < 8; i++)
    #pragma unroll
    for (int j = 0; j < 8; j++) acc[i][j] = 0.f;
  #pragma unroll 1
  for (int stage = 0; stage < 4; stage++){
    if (stage) __syncthreads();
    {
      int r = t >> 1, dc = (t & 1) * 8;
      const float4* pa = (const float4*)(fb + (size_t)(q0 + r)*HD + stage*16 + dc);
      const float4* pb = (const float4*)(fb + (size_t)(m0 + r)*HD + stage*16 + dc);
      #pragma unroll
      for (int i = 0; i < 2; i++){
        float4 va = pa[i], vb = pb[i];
        int d = dc + i*4;
        As[d][r]=va.x; As[d+1][r]=va.y; As[d+2][r]=va.z; As[d+3][r]=va.w;
        Bs[d][r]=vb.x; Bs[d+1][r]=vb.y; Bs[d+2][r]=vb.z; Bs[d+3][r]=vb.w;
      }
    }
    __syncthreads();
    #pragma unroll 2
    for (int d = 0; d < 16; d++){
      float af[8], bf[8];
      *(float4*)&af[0] = *(const float4*)&As[d][ty*8];
      *(float4*)&af[4] = *(const float4*)&As[d][ty*8+4];
      *(float4*)&bf[0] = *(const float4*)&Bs[d][tx*8];
      *(float4*)&bf[4] = *(const float4*)&Bs[d][tx*8+4];
      #pragma unroll
      for (int i = 0; i < 8; i++)
        #pragma unroll
        for (int j = 0; j < 8; j++)
          acc[i][j] = fmaf(af[i], bf[j], acc[i][j]);
    }
  }
  float sqv[8];
  {
    const float4* sp = (const float4*)(sqn + (size_t)b*NPB + m0 + tx*8);
    float4 sq0 = sp[0], sq1 = sp[1];
    sqv[0]=sq0.x; sqv[1]=sq0.y; sqv[2]=sq0.z; sqv[3]=sq0.w;
    sqv[4]=sq1.x; sqv[5]=sq1.y; sqv[6]=sq1.z; sqv[7]=sq1.w;
  }
  const float INF = 3.4e38f;
  #pragma unroll
  for (int i = 0; i < 8; i++){
    int qg = q0 + ty*8 + i;        // in-batch query index
    int cex = qg - m0;             // diagonal local cand (may be out of range)
    float s0=INF, s1=INF;
    int i0=0, i1=0;
    #pragma unroll
    for (int j = 0; j < 8; j++){
      int c = tx*8 + j;
      float v = fmaf(-2.f, acc[i][j], sqv[j]);
      if (c == cex) v = INF;
      bool l1 = v < s1, l0 = v < s0;
      s1 = l0 ? s0 : (l1 ? v : s1);  i1 = l0 ? i0 : (l1 ? c : i1);
      s0 = l0 ? v : s0;              i0 = l0 ? c : i0;
    }
    // 2-level merge of sorted-2 lists across the 4 lanes of the 32-cand group
    #pragma unroll
    for (int off = 1; off < 4; off <<= 1){
      float b0 = __shfl_xor(s0,off,64), b1 = __shfl_xor(s1,off,64);
      int  bj0 = __shfl_xor(i0,off,64), bj1 = __shfl_xor(i1,off,64);
      bool c0 = s0 <= b0;
      float w0 = c0 ? s0 : b0;  int x0 = c0 ? i0 : bj0;
      float z  = c0 ? b0 : s0;  int zi = c0 ? bj0 : i0;
      bool c1 = s1 <= b1;
      float m1 = c1 ? s1 : b1;  int mi = c1 ? i1 : bj1;
      bool c2 = z <= m1;
      float w1 = c2 ? z : m1;   int x1 = c2 ? zi : mi;
      s0 = w0; i0 = x0; s1 = w1; i1 = x1;
    }
    if ((tx & 3) == 0){
      size_t g = (size_t)b*NPB + qg;
      int entry = blockIdx.x*8 + (tx >> 2)*2;   // tile*8 + group*2
      float2 ov; ov.x = s0; ov.y = s1;
      *(float2*)(topv + g*192 + entry) = ov;
      uchar2 oi; oi.x = (unsigned char)i0; oi.y = (unsigned char)i1;
      *(uchar2*)(topi + g*192 + entry) = oi;
    }
  }
}

// ---------------- exact top-20 from per-group top-2 summaries ----------------
// One wave per query. 192 entries (24 tiles x 4 groups x 2). T = 20th smallest
// of 64 lane-minima (subset => T >= v20). Group unflagged (stored 2nd > T) =>
// its only <=T value is the stored min; flagged groups (stored 2nd <= T) are
// recomputed over their 32 cands with the bitwise-identical fma chain.
__global__ __launch_bounds__(256) void ksel_kernel(const float* __restrict__ topv,
    const unsigned char* __restrict__ topi, const float* __restrict__ feat,
    const float* __restrict__ sqn, int* __restrict__ idxout){
  __shared__ float cvs[4][72];
  __shared__ int   cxs[4][72];
  int wid = threadIdx.x >> 6, lane = threadIdx.x & 63;
  int g = blockIdx.x*4 + wid;
  int b = g / NPB;
  int ql = g - b*NPB;
  const float INF = 3.4e38f;
  const float* tv = topv + (size_t)g*192;
  const unsigned char* ti = topi + (size_t)g*192;
  float v0 = tv[lane],     v1 = tv[64+lane],    v2 = tv[128+lane];
  int   j0 = ti[lane],     j1 = ti[64+lane],    j2 = ti[128+lane];
  // threshold: 20th smallest of the 64 lane minima
  float T;
  {
    float v = fminf(v0, fminf(v1, v2));
    #pragma unroll
    for (int k = 2; k <= 64; k <<= 1){
      #pragma unroll
      for (int j = k >> 1; j > 0; j >>= 1){
        float o = __shfl_xor(v, j, 64);
        bool up    = ((lane & k) == 0);
        bool lower = ((lane & j) == 0);
        float mn = fminf(v, o), mx = fmaxf(v, o);
        v = (lower == up) ? mn : mx;
      }
    }
    T = __shfl(v, 19, 64);
  }
  // partner (the group's stored 2nd) for even-lane entries
  float p0 = __shfl_xor(v0, 1, 64);
  float p1 = __shfl_xor(v1, 1, 64);
  float p2 = __shfl_xor(v2, 1, 64);
  bool even = ((lane & 1) == 0);
  // collect minima of unflagged groups (even entry <= T, partner 2nd > T)
  float* cv = cvs[wid]; int* cx = cxs[wid];
  int base = 0;
  {
    bool f = even && (v0 <= T) && (p0 > T);
    unsigned long long mk = __ballot(f);
    int pos = (int)__popcll(mk & ((1ull<<lane)-1ull));
    if (f && pos < 64){ cv[pos] = v0; cx[pos] = ((lane>>3)<<7) + j0; }
    base = (int)__popcll(mk);
    f = even && (v1 <= T) && (p1 > T);
    mk = __ballot(f);
    pos = base + (int)__popcll(mk & ((1ull<<lane)-1ull));
    if (f && pos < 64){ cv[pos] = v1; cx[pos] = (((64+lane)>>3)<<7) + j1; }
    base += (int)__popcll(mk);
    f = even && (v2 <= T) && (p2 > T);
    mk = __ballot(f);
    pos = base + (int)__popcll(mk & ((1ull<<lane)-1ull));
    if (f && pos < 64){ cv[pos] = v2; cx[pos] = (((128+lane)>>3)<<7) + j2; }
    base += (int)__popcll(mk);
  }
  // flagged-group masks: odd entries <= T; bit position p=2*(g&31)+1
  unsigned long long fb0 = __ballot((lane & 1) && (v0 <= T));
  unsigned long long fb1 = __ballot((lane & 1) && (v1 <= T));
  unsigned long long fb2 = __ballot((lane & 1) && (v2 <= T));
  const float* fqp = feat + (size_t)g*HD;
  #pragma unroll 1
  for (int w = 0; w < 3; w++){
    unsigned long long fm = (w==0) ? fb0 : (w==1) ? fb1 : fb2;
    int gbase = w*32;
    while (fm){
      int p = __ffsll((unsigned long long)fm) - 1; fm &= fm - 1;
      int gg = gbase + (p >> 1);         // global group id 0..95
      int mbase = (gg >> 2)*128 + (gg & 3)*32;
      bool fire = false; float s = 0.f;
      if (lane < 32){
        int m = mbase + lane;
        const float* fmp = feat + (size_t)(b*NPB + m)*HD;
        float acc = 0.f;
        #pragma unroll
        for (int d4 = 0; d4 < 16; d4++){
          float4 fq4 = *(const float4*)(fqp + d4*4);
          float4 fm4 = *(const float4*)(fmp + d4*4);
          acc = fmaf(fq4.x, fm4.x, acc);
          acc = fmaf(fq4.y, fm4.y, acc);
          acc = fmaf(fq4.z, fm4.z, acc);
          acc = fmaf(fq4.w, fm4.w, acc);
        }
        s = fmaf(-2.f, acc, sqn[(size_t)b*NPB + m]);
        fire = (m != ql) && (s <= T);
      }
      unsigned long long mk2 = __ballot(fire);
      int p2 = base + (int)__popcll(mk2 & ((1ull<<lane)-1ull));
      if (fire && p2 < 64){ cv[p2] = s; cx[p2] = mbase + lane; }
      base += (int)__popcll(mk2);
    }
  }
  if (base <= 64){
    unsigned long long key;
    if (lane < base){
      unsigned int ku = __float_as_uint(cv[lane]);
      ku ^= (unsigned)(((int)ku) >> 31) | 0x80000000u;
      key = ((unsigned long long)ku << 32) | (unsigned int)cx[lane];
    } else key = ~0ull;
    #pragma unroll
    for (int k = 2; k <= 64; k <<= 1){
      #pragma unroll
      for (int j = k >> 1; j > 0; j >>= 1){
        unsigned long long o = __shfl_xor(key, j, 64);
        bool up    = ((lane & k) == 0);
        bool lower = ((lane & j) == 0);
        unsigned long long mn = key < o ? key : o;
        unsigned long long mx = key < o ? o : key;
        key = (lower == up) ? mn : mx;
      }
    }
    if (lane < KNN)
      idxout[(size_t)g*KNN + lane] = b*NPB + (int)(unsigned int)(key & 0xffffffffu);
  } else {
    // degenerate-tie fallback: full recompute, per-lane insert + 20-round merge
    float dl[KNN]; int il[KNN];
    #pragma unroll
    for (int k = 0; k < KNN; k++){ dl[k] = INF; il[k] = 0x7fffffff; }
    #pragma unroll 1
    for (int j = 0; j < 48; j++){
      int m = j*64 + lane;
      if (m == ql) continue;
      const float* fmp = feat + (size_t)(b*NPB + m)*HD;
      float acc = 0.f;
      for (int d4 = 0; d4 < 16; d4++){
        float4 fq4 = *(const float4*)(fqp + d4*4);
        float4 fm4 = *(const float4*)(fmp + d4*4);
        acc = fmaf(fq4.x, fm4.x, acc);
        acc = fmaf(fq4.y, fm4.y, acc);
        acc = fmaf(fq4.z, fm4.z, acc);
        acc = fmaf(fq4.w, fm4.w, acc);
      }
      float s = fmaf(-2.f, acc, sqn[(size_t)b*NPB + m]);
      if (s < dl[KNN-1]){
        #pragma unroll
        for (int k = KNN-1; k >= 1; k--){
          bool c1 = s < dl[k-1];
          bool c0 = s < dl[k];
          dl[k] = c1 ? dl[k-1] : (c0 ? s : dl[k]);
          il[k] = c1 ? il[k-1] : (c0 ? m : il[k]);
        }
        if (s < dl[0]){ dl[0] = s; il[0] = m; }
      }
    }
    int res = 0;
    #pragma unroll 1
    for (int r = 0; r < KNN; r++){
      float d = dl[0]; int i = il[0];
      #pragma unroll
      for (int off = 1; off < 64; off <<= 1){
        float od = __shfl_xor(d, off, 64);
        int   oi = __shfl_xor(i, off, 64);
        if (od < d || (od == d && oi < i)){ d = od; i = oi; }
      }
      if (lane == r) res = i;
      if (il[0] == i){
        #pragma unroll
        for (int k = 0; k < KNN-1; k++){ dl[k] = dl[k+1]; il[k] = il[k+1]; }
        dl[KNN-1] = INF; il[KNN-1] = 0x7fffffff;
      }
    }
    if (lane < KNN) idxout[(size_t)g*KNN + lane] = b*NPB + res;
  }
}

// ---------------- edge-conv factorization: u = x@(Wt-Wb)+b, v = x@Wb ----------------
__global__ __launch_bounds__(256) void uv_kernel(const float* __restrict__ feat,
    const float* __restrict__ W, const float* __restrict__ cb,
    float* __restrict__ u, float* __restrict__ v){
  __shared__ float sW[128*64];
  int t = threadIdx.x;
  for (int i = t; i < 8192; i += 256) sW[i] = W[i];
  __syncthreads();
  int n = blockIdx.x*256 + t;
  float4 fv[16];
  const float4* fp = (const float4*)(feat + (size_t)n*64);
  #pragma unroll
  for (int i = 0; i < 16; i++) fv[i] = fp[i];
  float4* up = (float4*)(u + (size_t)n*64);
  float4* vp = (float4*)(v + (size_t)n*64);
  #pragma unroll 1
  for (int c4 = 0; c4 < 16; c4++){
    float ua0=0,ua1=0,ua2=0,ua3=0, vb0=0,vb1=0,vb2=0,vb3=0;
    #pragma unroll
    for (int d4 = 0; d4 < 16; d4++){
      float4 fq = fv[d4];
      #pragma unroll
      for (int dd = 0; dd < 4; dd++){
        int d = d4*4 + dd;
        float fd = dd==0?fq.x : dd==1?fq.y : dd==2?fq.z : fq.w;
        float4 wt = *(const float4*)&sW[d*64 + c4*4];
        float4 wb = *(const float4*)&sW[(64+d)*64 + c4*4];
        ua0=fmaf(fd,wt.x,ua0); ua1=fmaf(fd,wt.y,ua1); ua2=fmaf(fd,wt.z,ua2); ua3=fmaf(fd,wt.w,ua3);
        vb0=fmaf(fd,wb.x,vb0); vb1=fmaf(fd,wb.y,vb1); vb2=fmaf(fd,wb.z,vb2); vb3=fmaf(fd,wb.w,vb3);
      }
    }
    float4 cbv = *(const float4*)&cb[c4*4];
    float4 uo, vo;
    uo.x = cbv.x + ua0 - vb0; uo.y = cbv.y + ua1 - vb1;
    uo.z = cbv.z + ua2 - vb2; uo.w = cbv.w + ua3 - vb3;
    vo.x = vb0; vo.y = vb1; vo.z = vb2; vo.w = vb3;
    up[c4] = uo; vp[c4] = vo;
  }
}

// ---------------- max-pool + BN + residual + sq of output (one wave per node) ----------------
__global__ __launch_bounds__(256) void pool_kernel(const float* __restrict__ u, const float* __restrict__ v,
    const int* __restrict__ idx, const float* __restrict__ resid,
    const float* __restrict__ bg, const float* __restrict__ bb,
    const float* __restrict__ bm, const float* __restrict__ bv,
    float* __restrict__ out, float* __restrict__ sqo){
  int gid = blockIdx.x*256 + threadIdx.x;
  int n = gid >> 6, lane = gid & 63;
  float uc = u[(size_t)n*64 + lane];
  float scale = bg[lane] / sqrtf(bv[lane] + 1e-5f);
  float bias  = bb[lane] - bm[lane]*scale;
  const int* ip = idx + (size_t)n*KNN;
  float acc = -3.4e38f;
  #pragma unroll 4
  for (int k = 0; k < KNN; k++){
    int j = ip[k];
    float s = uc + v[(size_t)j*64 + lane];
    acc = fmaxf(acc, fmaf(elu_f(s), scale, bias));
  }
  float val = acc + resid[(size_t)n*64 + lane];
  out[(size_t)n*64 + lane] = val;
  float ss = val*val;
  #pragma unroll
  for (int off = 1; off < 64; off <<= 1) ss += __shfl_xor(ss, off, 64);
  if (lane == 0) sqo[n] = ss;
}

// ---------------- CSR build over dst (edges + self loops) ----------------
__global__ void deg_init(int* deg){ int i = blockIdx.x*256 + threadIdx.x; if (i < NTOT) deg[i] = 1; }
__global__ void deg_hist(const int* __restrict__ ei, int E, int* deg){
  int i = blockIdx.x*256 + threadIdx.x; if (i < E) atomicAdd(&deg[ei[E + i]], 1);
}
__global__ void scan_kernel(const int* __restrict__ deg, int* __restrict__ rowptr, int* __restrict__ cursor){
  __shared__ int part[256];
  int t = threadIdx.x;
  int base = t*96;
  int s = 0;
  for (int i = 0; i < 96; i++) s += deg[base + i];
  part[t] = s;
  __syncthreads();
  for (int off = 1; off < 256; off <<= 1){
    int xv = (t >= off) ? part[t - off] : 0;
    __syncthreads();
    part[t] += xv;
    __syncthreads();
  }
  int run = part[t] - s;
  for (int i = 0; i < 96; i++){
    rowptr[base + i] = run; cursor[base + i] = run; run += deg[base + i];
  }
  if (t == 255) rowptr[NTOT] = run;
}
__global__ void scatter_kernel(const int* __restrict__ ei, int E, int* cursor, int* __restrict__ csr){
  int i = blockIdx.x*256 + threadIdx.x;
  if (i >= E + NTOT) return;
  int s, d;
  if (i < E){ s = ei[i]; d = ei[E + i]; } else { s = i - E; d = s; }
  int pos = atomicAdd(&cursor[d], 1);
  csr[pos] = s;
}

// ---------------- GAT: xh = x@W (NT,256), al_s/al_d per head ----------------
__global__ __launch_bounds__(256) void xh_kernel(const float* __restrict__ feat,
    const float* __restrict__ W, const float* __restrict__ asrc, const float* __restrict__ adst,
    float* __restrict__ xh, float* __restrict__ al){
  __shared__ float sW[64*128];
  __shared__ float sas[256], sad[256];
  int t = threadIdx.x;
  if (t < 256){ sas[t] = asrc[t]; sad[t] = adst[t]; }
  int n = blockIdx.x*256 + t;
  float4 fv[16];
  const float4* fp = (const float4*)(feat + (size_t)n*64);
  #pragma unroll
  for (int i = 0; i < 16; i++) fv[i] = fp[i];
  float4* xp = (float4*)(xh + (size_t)n*256);
  float* ap = al + (size_t)n*8;
  #pragma unroll 1
  for (int half = 0; half < 2; half++){
    __syncthreads();
    for (int i = t; i < 8192; i += 256){
      int d = i >> 7, c = i & 127;
      sW[i] = W[d*256 + half*128 + c];
    }
    __syncthreads();
    #pragma unroll 1
    for (int hh = 0; hh < 2; hh++){
      int h = half*2 + hh;
      float as_ = 0.f, ad_ = 0.f;
      #pragma unroll 1
      for (int cc = 0; cc < 64; cc += 4){
        int c  = h*64 + cc;
        int cl = hh*64 + cc;
        float a0=0,a1=0,a2=0,a3=0;
        #pragma unroll
        for (int d4 = 0; d4 < 16; d4++){
          float4 fq = fv[d4];
          #pragma unroll
          for (int dd = 0; dd < 4; dd++){
            int d = d4*4 + dd;
            float fd = dd==0?fq.x : dd==1?fq.y : dd==2?fq.z : fq.w;
            float4 wv = *(const float4*)&sW[d*128 + cl];
            a0=fmaf(fd,wv.x,a0); a1=fmaf(fd,wv.y,a1); a2=fmaf(fd,wv.z,a2); a3=fmaf(fd,wv.w,a3);
          }
        }
        float4 o; o.x=a0; o.y=a1; o.z=a2; o.w=a3;
        xp[c >> 2] = o;
        as_ = fmaf(a0, sas[c], fmaf(a1, sas[c+1], fmaf(a2, sas[c+2], fmaf(a3, sas[c+3], as_))));
        ad_ = fmaf(a0, sad[c], fmaf(a1, sad[c+1], fmaf(a2, sad[c+2], fmaf(a3, sad[c+3], ad_))));
      }
      ap[h] = as_; ap[4 + h] = ad_;
    }
  }
}

// ---------------- GAT aggregation: one-pass online softmax, one wave per dst ----------------
__global__ __launch_bounds__(256) void agg_kernel(const float* __restrict__ xh, const float* __restrict__ al,
    const int* __restrict__ rowptr, const int* __restrict__ csr,
    const float* __restrict__ resid, const float* __restrict__ bias,
    float* __restrict__ out){
  int gid = blockIdx.x*256 + threadIdx.x;
  int n = gid >> 6, lane = gid & 63;
  int rs = rowptr[n], re = rowptr[n+1];
  int h = lane >> 4, coff = (lane & 15)*4;
  float ald_h = al[(size_t)n*8 + 4 + h];
  float mx = -3.4e38f, den = 0.f;
  float ax=0.f, ay=0.f, az=0.f, aw=0.f;
  #pragma unroll 2
  for (int e = rs; e < re; e++){
    int s = csr[e];
    float a = al[(size_t)s*8 + h] + ald_h;
    a = a > 0.f ? a : 0.2f*a;                   // leaky_relu
    float nm = fmaxf(mx, a);
    float corr = __expf(mx - nm);
    float ea   = __expf(a - nm);
    mx = nm;
    float4 xv = *(const float4*)(xh + (size_t)s*256 + h*64 + coff);
    den = fmaf(den, corr, ea);
    ax = fmaf(ax, corr, ea*xv.x); ay = fmaf(ay, corr, ea*xv.y);
    az = fmaf(az, corr, ea*xv.z); aw = fmaf(aw, corr, ea*xv.w);
  }
  float rinv = 1.f / (den + 1e-16f);
  float r0 = ax*rinv, r1 = ay*rinv, r2 = az*rinv, r3 = aw*rinv;
  r0 += __shfl_xor(r0, 16, 64); r1 += __shfl_xor(r1, 16, 64);
  r2 += __shfl_xor(r2, 16, 64); r3 += __shfl_xor(r3, 16, 64);
  r0 += __shfl_xor(r0, 32, 64); r1 += __shfl_xor(r1, 32, 64);
  r2 += __shfl_xor(r2, 32, 64); r3 += __shfl_xor(r3, 32, 64);
  if (lane < 16){
    float4 bs = *(const float4*)(bias + coff);
    float4 rv = *(const float4*)(resid + (size_t)n*64 + coff);
    float4 o;
    o.x = r0*0.25f + bs.x + rv.x; o.y = r1*0.25f + bs.y + rv.y;
    o.z = r2*0.25f + bs.z + rv.z; o.w = r3*0.25f + bs.w + rv.w;
    *(float4*)(out + (size_t)n*64 + coff) = o;
  }
}

// ---------------- output MLP: 64->64 elu ->32 elu ->8 ----------------
__global__ __launch_bounds__(256) void mlp_kernel(const float* __restrict__ feat,
    const float* __restrict__ W1, const float* __restrict__ b1,
    const float* __restrict__ W2, const float* __restrict__ b2,
    const float* __restrict__ W3, const float* __restrict__ b3,
    float* __restrict__ out){
  __shared__ float s1[4096], s2[2048], s3[256], t1[64], t2[32], t3[8];
  int t = threadIdx.x;
  for (int i = t; i < 4096; i += 256) s1[i] = W1[i];
  for (int i = t; i < 2048; i += 256) s2[i] = W2[i];
  if (t < 256) s3[t] = W3[t];
  if (t < 64) t1[t] = b1[t];
  if (t < 32) t2[t] = b2[t];
  if (t < 8)  t3[t] = b3[t];
  __syncthreads();
  int n = blockIdx.x*256 + t;
  float4 fv[16];
  const float4* fp = (const float4*)(feat + (size_t)n*64);
  #pragma unroll
  for (int i = 0; i < 16; i++) fv[i] = fp[i];
  float o1[64];
  #pragma unroll 1
  for (int c4 = 0; c4 < 16; c4++){
    float a0=t1[c4*4+0], a1=t1[c4*4+1], a2=t1[c4*4+2], a3=t1[c4*4+3];
    #pragma unroll
    for (int d4 = 0; d4 < 16; d4++){
      float4 fq = fv[d4];
      #pragma unroll
      for (int dd = 0; dd < 4; dd++){
        int d = d4*4 + dd;
        float fd = dd==0?fq.x : dd==1?fq.y : dd==2?fq.z : fq.w;
        float4 wv = *(const float4*)&s1[d*64 + c4*4];
        a0=fmaf(fd,wv.x,a0); a1=fmaf(fd,wv.y,a1); a2=fmaf(fd,wv.z,a2); a3=fmaf(fd,wv.w,a3);
      }
    }
    o1[c4*4+0]=elu_f(a0); o1[c4*4+1]=elu_f(a1); o1[c4*4+2]=elu_f(a2); o1[c4*4+3]=elu_f(a3);
  }
  float o2[32];
  #pragma unroll 1
  for (int c4 = 0; c4 < 8; c4++){
    float a0=t2[c4*4+0], a1=t2[c4*4+1], a2=t2[c4*4+2], a3=t2[c4*4+3];
    #pragma unroll
    for (int d = 0; d < 64; d++){
      float fd = o1[d];
      float4 wv = *(const float4*)&s2[d*32 + c4*4];
      a0=fmaf(fd,wv.x,a0); a1=fmaf(fd,wv.y,a1); a2=fmaf(fd,wv.z,a2); a3=fmaf(fd,wv.w,a3);
    }
    o2[c4*4+0]=elu_f(a0); o2[c4*4+1]=elu_f(a1); o2[c4*4+2]=elu_f(a2); o2[c4*4+3]=elu_f(a3);
  }
  float4* op = (float4*)(out + (size_t)n*8);
  #pragma unroll
  for (int c4 = 0; c4 < 2; c4++){
    float a0=t3[c4*4+0], a1=t3[c4*4+1], a2=t3[c4*4+2], a3=t3[c4*4+3];
    #pragma unroll
    for (int d = 0; d < 32; d++){
      float fd = o2[d];
      float4 wv = *(const float4*)&s3[d*8 + c4*4];
      a0=fmaf(fd,wv.x,a0); a1=fmaf(fd,wv.y,a1); a2=fmaf(fd,wv.z,a2); a3=fmaf(fd,wv.w,a3);
    }
    float4 o; o.x=a0; o.y=a1; o.z=a2; o.w=a3;
    op[c4] = o;
  }
}

extern "C" void kernel_launch(void* const* d_in, const int* in_sizes, int n_in,
                              void* d_out, int out_size, void* d_ws, size_t ws_size,
                              hipStream_t stream){
  (void)n_in; (void)out_size; (void)ws_size;
  const float* x     = (const float*)d_in[0];
  const int*   ei    = (const int*)d_in[2];
  const int    E     = in_sizes[2] / 2;
  const float* encW1 = (const float*)d_in[3];
  const float* encb1 = (const float*)d_in[4];
  const float* encW2 = (const float*)d_in[5];
  const float* encb2 = (const float*)d_in[6];
  const float* convW = (const float*)d_in[7];
  const float* convb = (const float*)d_in[8];
  const float* bng   = (const float*)d_in[9];
  const float* bnb   = (const float*)d_in[10];
  const float* bnm   = (const float*)d_in[11];
  const float* bnv   = (const float*)d_in[12];
  const float* gatW  = (const float*)d_in[13];
  const float* gatas = (const float*)d_in[14];
  const float* gatad = (const float*)d_in[15];
  const float* gatb  = (const float*)d_in[16];
  const float* oW1   = (const float*)d_in[17];
  const float* ob1   = (const float*)d_in[18];
  const float* oW2   = (const float*)d_in[19];
  const float* ob2   = (const float*)d_in[20];
  const float* oW3   = (const float*)d_in[21];
  const float* ob3   = (const float*)d_in[22];

  char* wp = (char*)d_ws;
  auto alloc = [&](size_t bytes)->void*{
    void* p = (void*)wp; wp += (bytes + 255) & ~((size_t)255); return p;
  };
  float* fA     = (float*)alloc((size_t)NTOT*64*4);
  float* fB     = (float*)alloc((size_t)NTOT*64*4);
  float* ubuf   = (float*)alloc((size_t)NTOT*64*4);
  float* vbuf   = (float*)alloc((size_t)NTOT*64*4);
  float* sqb    = (float*)alloc((size_t)NTOT*4);
  int*   idxb   = (int*)  alloc((size_t)NTOT*KNN*4);
  float* xhb    = (float*)alloc((size_t)NTOT*256*4);
  float* alb    = (float*)alloc((size_t)NTOT*8*4);
  int*   degb   = (int*)  alloc((size_t)NTOT*4);
  int*   rowptr = (int*)  alloc((size_t)(NTOT+1)*4);
  int*   cursor = (int*)  alloc((size_t)NTOT*4);
  int*   csr    = (int*)  alloc((size_t)(E+NTOT)*4);
  float* topv   = (float*)alloc((size_t)NTOT*192*4);
  unsigned char* topi = (unsigned char*)alloc((size_t)NTOT*192);

  enc_kernel<<<96,256,0,stream>>>(x, encW1, encb1, encW2, encb2, fA, sqb);
  float* cur = fA; float* nxt = fB;
  for (int l = 0; l < 3; l++){
    disttop_kernel<<<dim3(NTILE,NTILE,NB),256,0,stream>>>(cur, sqb, topv, topi);
    ksel_kernel   <<<NTOT/4,              256,0,stream>>>(topv, topi, cur, sqb, idxb);
    uv_kernel  <<<96,  256,0,stream>>>(cur, convW + (size_t)l*8192, convb + l*64, ubuf, vbuf);
    pool_kernel<<<6144,256,0,stream>>>(ubuf, vbuf, idxb, cur,
                                       bng + l*64, bnb + l*64, bnm + l*64, bnv + l*64, nxt, sqb);
    float* tmp = cur; cur = nxt; nxt = tmp;
  }
  deg_init   <<<96,            256,0,stream>>>(degb);
  deg_hist   <<<(E+255)/256,   256,0,stream>>>(ei, E, degb);
  scan_kernel<<<1,             256,0,stream>>>(degb, rowptr, cursor);
  scatter_kernel<<<(E+NTOT+255)/256,256,0,stream>>>(ei, E, cursor, csr);
  for (int l = 0; l < 2; l++){
    xh_kernel <<<96,  256,0,stream>>>(cur, gatW + (size_t)l*16384, gatas + l*256, gatad + l*256, xhb, alb);
    agg_kernel<<<6144,256,0,stream>>>(xhb, alb, rowptr, csr, cur, gatb + l*64, nxt);
    float* tmp = cur; cur = nxt; nxt = tmp;
  }
  mlp_kernel<<<96,256,0,stream>>>(cur, oW1, ob1, oW2, ob2, oW3, ob3, (float*)d_out);
}

// Round 12
// 1286.899 us; speedup vs baseline: 1.0104x; 1.0104x over previous
//
#include <hip/hip_runtime.h>
#include <math.h>

// Problem constants (match reference)
#define NTOT  24576      // B*N nodes
#define NB    8
#define NPB   3072       // nodes per batch
#define HD    64
#define KNN   20
#define NTILE 24         // NPB/128

__device__ __forceinline__ float elu_f(float x){ return x > 0.f ? x : expm1f(x); }

// ---------------- encoder: x(NT,8) -> elu(elu(x@W1+b1)@W2+b2) (NT,64) + sq ----------------
__global__ __launch_bounds__(256) void enc_kernel(const float* __restrict__ x,
    const float* __restrict__ W1, const float* __restrict__ b1,
    const float* __restrict__ W2, const float* __restrict__ b2,
    float* __restrict__ out, float* __restrict__ sqo){
  __shared__ float sW1[256], sb1[32], sW2[2048], sb2[64];
  int t = threadIdx.x;
  if (t < 256) sW1[t] = W1[t];
  for (int i = t; i < 2048; i += 256) sW2[i] = W2[i];
  if (t < 32) sb1[t] = b1[t];
  if (t < 64) sb2[t] = b2[t];
  __syncthreads();
  int n = blockIdx.x*256 + t;
  const float4* xp = (const float4*)(x + (size_t)n*8);
  float4 x0 = xp[0], x1 = xp[1];
  float xi[8] = {x0.x,x0.y,x0.z,x0.w,x1.x,x1.y,x1.z,x1.w};
  float h1[32];
  #pragma unroll
  for (int j = 0; j < 32; j++){
    float a = sb1[j];
    #pragma unroll
    for (int d = 0; d < 8; d++) a = fmaf(xi[d], sW1[d*32+j], a);
    h1[j] = elu_f(a);
  }
  float4* op = (float4*)(out + (size_t)n*64);
  float ssum = 0.f;
  #pragma unroll
  for (int c4 = 0; c4 < 16; c4++){
    float a0 = sb2[c4*4+0], a1 = sb2[c4*4+1], a2 = sb2[c4*4+2], a3 = sb2[c4*4+3];
    #pragma unroll
    for (int d = 0; d < 32; d++){
      float hd = h1[d];
      float4 wv = *(const float4*)&sW2[d*64 + c4*4];
      a0 = fmaf(hd, wv.x, a0); a1 = fmaf(hd, wv.y, a1);
      a2 = fmaf(hd, wv.z, a2); a3 = fmaf(hd, wv.w, a3);
    }
    float4 o; o.x=elu_f(a0); o.y=elu_f(a1); o.z=elu_f(a2); o.w=elu_f(a3);
    ssum = fmaf(o.x,o.x,ssum); ssum = fmaf(o.y,o.y,ssum);
    ssum = fmaf(o.z,o.z,ssum); ssum = fmaf(o.w,o.w,ssum);
    op[c4] = o;
  }
  sqo[n] = ssum;
}

// ---------------- fused distance GEMM + per-32-group top-2 (K-split depth 16) ----------------
// grid = dim3(24, 24, NB). Block: 128q x 128c tile, 8x8 acc per thread.
// Summaries: per (row, 32-cand group) the 2 smallest values + local idx.
// Per row: branchless top-2 insert over the thread's 8 cands, then 2-level
// shfl_xor(1,2) sorted-2 merge across the 4 lanes of the group.
__global__ __launch_bounds__(256) void disttop_kernel(const float* __restrict__ feat,
    const float* __restrict__ sqn, float* __restrict__ topv, unsigned char* __restrict__ topi){
  __shared__ float As[16][128];
  __shared__ float Bs[16][128];
  int b  = blockIdx.z;
  int m0 = blockIdx.x * 128;
  int q0 = blockIdx.y * 128;
  const float* fb = feat + (size_t)b*NPB*HD;
  int t = threadIdx.x;
  int tx = t & 15, ty = t >> 4;
  float acc[8][8];
  #pragma unroll
  for (int i = 0; i < 8; i++)
    #pragma unroll
    for (int j = 0; j < 8; j++) acc[i][j] = 0.f;
  #pragma unroll 1
  for (int stage = 0; stage < 4; stage++){
    if (stage) __syncthreads();
    {
      int r = t >> 1, dc = (t & 1) * 8;
      const float4* pa = (const float4*)(fb + (size_t)(q0 + r)*HD + stage*16 + dc);
      const float4* pb = (const float4*)(fb + (size_t)(m0 + r)*HD + stage*16 + dc);
      #pragma unroll
      for (int i = 0; i < 2; i++){
        float4 va = pa[i], vb = pb[i];
        int d = dc + i*4;
        As[d][r]=va.x; As[d+1][r]=va.y; As[d+2][r]=va.z; As[d+3][r]=va.w;
        Bs[d][r]=vb.x; Bs[d+1][r]=vb.y; Bs[d+2][r]=vb.z; Bs[d+3][r]=vb.w;
      }
    }
    __syncthreads();
    #pragma unroll 2
    for (int d = 0; d < 16; d++){
      float af[8], bf[8];
      *(float4*)&af[0] = *(const float4*)&As[d][ty*8];
      *(float4*)&af[4] = *(const float4*)&As[d][ty*8+4];
      *(float4*)&bf[0] = *(const float4*)&Bs[d][tx*8];
      *(float4*)&bf[4] = *(const float4*)&Bs[d][tx*8+4];
      #pragma unroll
      for (int i = 0; i < 8; i++)
        #pragma unroll
        for (int j = 0; j < 8; j++)
          acc[i][j] = fmaf(af[i], bf[j], acc[i][j]);
    }
  }
  float sqv[8];
  {
    const float4* sp = (const float4*)(sqn + (size_t)b*NPB + m0 + tx*8);
    float4 sq0 = sp[0], sq1 = sp[1];
    sqv[0]=sq0.x; sqv[1]=sq0.y; sqv[2]=sq0.z; sqv[3]=sq0.w;
    sqv[4]=sq1.x; sqv[5]=sq1.y; sqv[6]=sq1.z; sqv[7]=sq1.w;
  }
  const float INF = 3.4e38f;
  #pragma unroll
  for (int i = 0; i < 8; i++){
    int qg = q0 + ty*8 + i;        // in-batch query index
    int cex = qg - m0;             // diagonal local cand (may be out of range)
    float s0=INF, s1=INF;
    int i0=0, i1=0;
    #pragma unroll
    for (int j = 0; j < 8; j++){
      int c = tx*8 + j;
      float v = fmaf(-2.f, acc[i][j], sqv[j]);
      if (c == cex) v = INF;
      bool l1 = v < s1, l0 = v < s0;
      s1 = l0 ? s0 : (l1 ? v : s1);  i1 = l0 ? i0 : (l1 ? c : i1);
      s0 = l0 ? v : s0;              i0 = l0 ? c : i0;
    }
    // 2-level merge of sorted-2 lists across the 4 lanes of the 32-cand group
    #pragma unroll
    for (int off = 1; off < 4; off <<= 1){
      float b0 = __shfl_xor(s0,off,64), b1 = __shfl_xor(s1,off,64);
      int  bj0 = __shfl_xor(i0,off,64), bj1 = __shfl_xor(i1,off,64);
      bool c0 = s0 <= b0;
      float w0 = c0 ? s0 : b0;  int x0 = c0 ? i0 : bj0;
      float z  = c0 ? b0 : s0;  int zi = c0 ? bj0 : i0;
      bool c1 = s1 <= b1;
      float m1 = c1 ? s1 : b1;  int mi = c1 ? i1 : bj1;
      bool c2 = z <= m1;
      float w1 = c2 ? z : m1;   int x1 = c2 ? zi : mi;
      s0 = w0; i0 = x0; s1 = w1; i1 = x1;
    }
    if ((tx & 3) == 0){
      size_t g = (size_t)b*NPB + qg;
      int entry = blockIdx.x*8 + (tx >> 2)*2;   // tile*8 + group*2
      float2 ov; ov.x = s0; ov.y = s1;
      *(float2*)(topv + g*192 + entry) = ov;
      uchar2 oi; oi.x = (unsigned char)i0; oi.y = (unsigned char)i1;
      *(uchar2*)(topi + g*192 + entry) = oi;
    }
  }
}

// ---------------- exact top-20 from per-group top-2 summaries ----------------
// One wave per query. 192 entries (24 tiles x 4 groups x 2). T = 20th smallest
// of the 96 GROUP MINIMA (paired via shfl into 64 lane values) — actual row
// values, so T >= v20. Group unflagged (stored 2nd > T) => its only <=T value
// is the stored min; flagged groups are recomputed over their 32 cands with
// the bitwise-identical fma chain. Lex bitonic -> exact top-20.
__global__ __launch_bounds__(256) void ksel_kernel(const float* __restrict__ topv,
    const unsigned char* __restrict__ topi, const float* __restrict__ feat,
    const float* __restrict__ sqn, int* __restrict__ idxout){
  __shared__ float cvs[4][72];
  __shared__ int   cxs[4][72];
  int wid = threadIdx.x >> 6, lane = threadIdx.x & 63;
  int g = blockIdx.x*4 + wid;
  int b = g / NPB;
  int ql = g - b*NPB;
  const float INF = 3.4e38f;
  const float* tv = topv + (size_t)g*192;
  const unsigned char* ti = topi + (size_t)g*192;
  float v0 = tv[lane],     v1 = tv[64+lane],    v2 = tv[128+lane];
  int   j0 = ti[lane],     j1 = ti[64+lane],    j2 = ti[128+lane];
  // threshold: 20th smallest of the 96 group minima (even entries).
  // lane l gets groupmin[l] (entry 2l: from v0/v1 words) and, for l<32,
  // groupmin[64+l] (entry 128+2l: from v2 word) via shuffles.
  float T;
  {
    int src = (2*lane) & 63;
    float a0 = __shfl(v0, src, 64);
    float a1 = __shfl(v1, src, 64);
    float a2 = __shfl(v2, src, 64);
    float m1 = (lane < 32) ? a0 : a1;
    float m2 = (lane < 32) ? a2 : INF;
    float v = fminf(m1, m2);
    #pragma unroll
    for (int k = 2; k <= 64; k <<= 1){
      #pragma unroll
      for (int j = k >> 1; j > 0; j >>= 1){
        float o = __shfl_xor(v, j, 64);
        bool up    = ((lane & k) == 0);
        bool lower = ((lane & j) == 0);
        float mn = fminf(v, o), mx = fmaxf(v, o);
        v = (lower == up) ? mn : mx;
      }
    }
    T = __shfl(v, 19, 64);
  }
  // partner (the group's stored 2nd) for even-lane entries
  float p0 = __shfl_xor(v0, 1, 64);
  float p1 = __shfl_xor(v1, 1, 64);
  float p2 = __shfl_xor(v2, 1, 64);
  bool even = ((lane & 1) == 0);
  // collect minima of unflagged groups (even entry <= T, partner 2nd > T)
  float* cv = cvs[wid]; int* cx = cxs[wid];
  int base = 0;
  {
    bool f = even && (v0 <= T) && (p0 > T);
    unsigned long long mk = __ballot(f);
    int pos = (int)__popcll(mk & ((1ull<<lane)-1ull));
    if (f && pos < 64){ cv[pos] = v0; cx[pos] = ((lane>>3)<<7) + j0; }
    base = (int)__popcll(mk);
    f = even && (v1 <= T) && (p1 > T);
    mk = __ballot(f);
    pos = base + (int)__popcll(mk & ((1ull<<lane)-1ull));
    if (f && pos < 64){ cv[pos] = v1; cx[pos] = (((64+lane)>>3)<<7) + j1; }
    base += (int)__popcll(mk);
    f = even && (v2 <= T) && (p2 > T);
    mk = __ballot(f);
    pos = base + (int)__popcll(mk & ((1ull<<lane)-1ull));
    if (f && pos < 64){ cv[pos] = v2; cx[pos] = (((128+lane)>>3)<<7) + j2; }
    base += (int)__popcll(mk);
  }
  // flagged-group masks: odd entries <= T; bit position p = 2*(g&31)+1
  unsigned long long fb0 = __ballot((lane & 1) && (v0 <= T));
  unsigned long long fb1 = __ballot((lane & 1) && (v1 <= T));
  unsigned long long fb2 = __ballot((lane & 1) && (v2 <= T));
  const float* fqp = feat + (size_t)g*HD;
  #pragma unroll 1
  for (int w = 0; w < 3; w++){
    unsigned long long fm = (w==0) ? fb0 : (w==1) ? fb1 : fb2;
    int gbase = w*32;
    while (fm){
      int p = __ffsll((unsigned long long)fm) - 1; fm &= fm - 1;
      int gg = gbase + (p >> 1);         // global group id 0..95
      int mbase = (gg >> 2)*128 + (gg & 3)*32;
      bool fire = false; float s = 0.f;
      if (lane < 32){
        int m = mbase + lane;
        const float* fmp = feat + (size_t)(b*NPB + m)*HD;
        float acc = 0.f;
        #pragma unroll
        for (int d4 = 0; d4 < 16; d4++){
          float4 fq4 = *(const float4*)(fqp + d4*4);
          float4 fm4 = *(const float4*)(fmp + d4*4);
          acc = fmaf(fq4.x, fm4.x, acc);
          acc = fmaf(fq4.y, fm4.y, acc);
          acc = fmaf(fq4.z, fm4.z, acc);
          acc = fmaf(fq4.w, fm4.w, acc);
        }
        s = fmaf(-2.f, acc, sqn[(size_t)b*NPB + m]);
        fire = (m != ql) && (s <= T);
      }
      unsigned long long mk2 = __ballot(fire);
      int p2 = base + (int)__popcll(mk2 & ((1ull<<lane)-1ull));
      if (fire && p2 < 64){ cv[p2] = s; cx[p2] = mbase + lane; }
      base += (int)__popcll(mk2);
    }
  }
  if (base <= 64){
    unsigned long long key;
    if (lane < base){
      unsigned int ku = __float_as_uint(cv[lane]);
      ku ^= (unsigned)(((int)ku) >> 31) | 0x80000000u;
      key = ((unsigned long long)ku << 32) | (unsigned int)cx[lane];
    } else key = ~0ull;
    #pragma unroll
    for (int k = 2; k <= 64; k <<= 1){
      #pragma unroll
      for (int j = k >> 1; j > 0; j >>= 1){
        unsigned long long o = __shfl_xor(key, j, 64);
        bool up    = ((lane & k) == 0);
        bool lower = ((lane & j) == 0);
        unsigned long long mn = key < o ? key : o;
        unsigned long long mx = key < o ? o : key;
        key = (lower == up) ? mn : mx;
      }
    }
    if (lane < KNN)
      idxout[(size_t)g*KNN + lane] = b*NPB + (int)(unsigned int)(key & 0xffffffffu);
  } else {
    // degenerate-tie fallback: full recompute, per-lane insert + 20-round merge
    float dl[KNN]; int il[KNN];
    #pragma unroll
    for (int k = 0; k < KNN; k++){ dl[k] = INF; il[k] = 0x7fffffff; }
    #pragma unroll 1
    for (int j = 0; j < 48; j++){
      int m = j*64 + lane;
      if (m == ql) continue;
      const float* fmp = feat + (size_t)(b*NPB + m)*HD;
      float acc = 0.f;
      for (int d4 = 0; d4 < 16; d4++){
        float4 fq4 = *(const float4*)(fqp + d4*4);
        float4 fm4 = *(const float4*)(fmp + d4*4);
        acc = fmaf(fq4.x, fm4.x, acc);
        acc = fmaf(fq4.y, fm4.y, acc);
        acc = fmaf(fq4.z, fm4.z, acc);
        acc = fmaf(fq4.w, fm4.w, acc);
      }
      float s = fmaf(-2.f, acc, sqn[(size_t)b*NPB + m]);
      if (s < dl[KNN-1]){
        #pragma unroll
        for (int k = KNN-1; k >= 1; k--){
          bool c1 = s < dl[k-1];
          bool c0 = s < dl[k];
          dl[k] = c1 ? dl[k-1] : (c0 ? s : dl[k]);
          il[k] = c1 ? il[k-1] : (c0 ? m : il[k]);
        }
        if (s < dl[0]){ dl[0] = s; il[0] = m; }
      }
    }
    int res = 0;
    #pragma unroll 1
    for (int r = 0; r < KNN; r++){
      float d = dl[0]; int i = il[0];
      #pragma unroll
      for (int off = 1; off < 64; off <<= 1){
        float od = __shfl_xor(d, off, 64);
        int   oi = __shfl_xor(i, off, 64);
        if (od < d || (od == d && oi < i)){ d = od; i = oi; }
      }
      if (lane == r) res = i;
      if (il[0] == i){
        #pragma unroll
        for (int k = 0; k < KNN-1; k++){ dl[k] = dl[k+1]; il[k] = il[k+1]; }
        dl[KNN-1] = INF; il[KNN-1] = 0x7fffffff;
      }
    }
    if (lane < KNN) idxout[(size_t)g*KNN + lane] = b*NPB + res;
  }
}

// ---------------- edge-conv factorization: u = x@(Wt-Wb)+b, v = x@Wb ----------------
__global__ __launch_bounds__(256) void uv_kernel(const float* __restrict__ feat,
    const float* __restrict__ W, const float* __restrict__ cb,
    float* __restrict__ u, float* __restrict__ v){
  __shared__ float sW[128*64];
  int t = threadIdx.x;
  for (int i = t; i < 8192; i += 256) sW[i] = W[i];
  __syncthreads();
  int n = blockIdx.x*256 + t;
  float4 fv[16];
  const float4* fp = (const float4*)(feat + (size_t)n*64);
  #pragma unroll
  for (int i = 0; i < 16; i++) fv[i] = fp[i];
  float4* up = (float4*)(u + (size_t)n*64);
  float4* vp = (float4*)(v + (size_t)n*64);
  #pragma unroll 1
  for (int c4 = 0; c4 < 16; c4++){
    float ua0=0,ua1=0,ua2=0,ua3=0, vb0=0,vb1=0,vb2=0,vb3=0;
    #pragma unroll
    for (int d4 = 0; d4 < 16; d4++){
      float4 fq = fv[d4];
      #pragma unroll
      for (int dd = 0; dd < 4; dd++){
        int d = d4*4 + dd;
        float fd = dd==0?fq.x : dd==1?fq.y : dd==2?fq.z : fq.w;
        float4 wt = *(const float4*)&sW[d*64 + c4*4];
        float4 wb = *(const float4*)&sW[(64+d)*64 + c4*4];
        ua0=fmaf(fd,wt.x,ua0); ua1=fmaf(fd,wt.y,ua1); ua2=fmaf(fd,wt.z,ua2); ua3=fmaf(fd,wt.w,ua3);
        vb0=fmaf(fd,wb.x,vb0); vb1=fmaf(fd,wb.y,vb1); vb2=fmaf(fd,wb.z,vb2); vb3=fmaf(fd,wb.w,vb3);
      }
    }
    float4 cbv = *(const float4*)&cb[c4*4];
    float4 uo, vo;
    uo.x = cbv.x + ua0 - vb0; uo.y = cbv.y + ua1 - vb1;
    uo.z = cbv.z + ua2 - vb2; uo.w = cbv.w + ua3 - vb3;
    vo.x = vb0; vo.y = vb1; vo.z = vb2; vo.w = vb3;
    up[c4] = uo; vp[c4] = vo;
  }
}

// ---------------- max-pool + BN + residual + sq of output (one wave per node) ----------------
__global__ __launch_bounds__(256) void pool_kernel(const float* __restrict__ u, const float* __restrict__ v,
    const int* __restrict__ idx, const float* __restrict__ resid,
    const float* __restrict__ bg, const float* __restrict__ bb,
    const float* __restrict__ bm, const float* __restrict__ bv,
    float* __restrict__ out, float* __restrict__ sqo){
  int gid = blockIdx.x*256 + threadIdx.x;
  int n = gid >> 6, lane = gid & 63;
  float uc = u[(size_t)n*64 + lane];
  float scale = bg[lane] / sqrtf(bv[lane] + 1e-5f);
  float bias  = bb[lane] - bm[lane]*scale;
  const int* ip = idx + (size_t)n*KNN;
  float acc = -3.4e38f;
  #pragma unroll 4
  for (int k = 0; k < KNN; k++){
    int j = ip[k];
    float s = uc + v[(size_t)j*64 + lane];
    acc = fmaxf(acc, fmaf(elu_f(s), scale, bias));
  }
  float val = acc + resid[(size_t)n*64 + lane];
  out[(size_t)n*64 + lane] = val;
  float ss = val*val;
  #pragma unroll
  for (int off = 1; off < 64; off <<= 1) ss += __shfl_xor(ss, off, 64);
  if (lane == 0) sqo[n] = ss;
}

// ---------------- CSR build over dst (edges + self loops) ----------------
__global__ void deg_init(int* deg){ int i = blockIdx.x*256 + threadIdx.x; if (i < NTOT) deg[i] = 1; }
__global__ void deg_hist(const int* __restrict__ ei, int E, int* deg){
  int i = blockIdx.x*256 + threadIdx.x; if (i < E) atomicAdd(&deg[ei[E + i]], 1);
}
__global__ void scan_kernel(const int* __restrict__ deg, int* __restrict__ rowptr, int* __restrict__ cursor){
  __shared__ int part[256];
  int t = threadIdx.x;
  int base = t*96;
  int s = 0;
  for (int i = 0; i < 96; i++) s += deg[base + i];
  part[t] = s;
  __syncthreads();
  for (int off = 1; off < 256; off <<= 1){
    int xv = (t >= off) ? part[t - off] : 0;
    __syncthreads();
    part[t] += xv;
    __syncthreads();
  }
  int run = part[t] - s;
  for (int i = 0; i < 96; i++){
    rowptr[base + i] = run; cursor[base + i] = run; run += deg[base + i];
  }
  if (t == 255) rowptr[NTOT] = run;
}
__global__ void scatter_kernel(const int* __restrict__ ei, int E, int* cursor, int* __restrict__ csr){
  int i = blockIdx.x*256 + threadIdx.x;
  if (i >= E + NTOT) return;
  int s, d;
  if (i < E){ s = ei[i]; d = ei[E + i]; } else { s = i - E; d = s; }
  int pos = atomicAdd(&cursor[d], 1);
  csr[pos] = s;
}

// ---------------- GAT: xh = x@W (NT,256), al_s/al_d per head ----------------
__global__ __launch_bounds__(256) void xh_kernel(const float* __restrict__ feat,
    const float* __restrict__ W, const float* __restrict__ asrc, const float* __restrict__ adst,
    float* __restrict__ xh, float* __restrict__ al){
  __shared__ float sW[64*128];
  __shared__ float sas[256], sad[256];
  int t = threadIdx.x;
  if (t < 256){ sas[t] = asrc[t]; sad[t] = adst[t]; }
  int n = blockIdx.x*256 + t;
  float4 fv[16];
  const float4* fp = (const float4*)(feat + (size_t)n*64);
  #pragma unroll
  for (int i = 0; i < 16; i++) fv[i] = fp[i];
  float4* xp = (float4*)(xh + (size_t)n*256);
  float* ap = al + (size_t)n*8;
  #pragma unroll 1
  for (int half = 0; half < 2; half++){
    __syncthreads();
    for (int i = t; i < 8192; i += 256){
      int d = i >> 7, c = i & 127;
      sW[i] = W[d*256 + half*128 + c];
    }
    __syncthreads();
    #pragma unroll 1
    for (int hh = 0; hh < 2; hh++){
      int h = half*2 + hh;
      float as_ = 0.f, ad_ = 0.f;
      #pragma unroll 1
      for (int cc = 0; cc < 64; cc += 4){
        int c  = h*64 + cc;
        int cl = hh*64 + cc;
        float a0=0,a1=0,a2=0,a3=0;
        #pragma unroll
        for (int d4 = 0; d4 < 16; d4++){
          float4 fq = fv[d4];
          #pragma unroll
          for (int dd = 0; dd < 4; dd++){
            int d = d4*4 + dd;
            float fd = dd==0?fq.x : dd==1?fq.y : dd==2?fq.z : fq.w;
            float4 wv = *(const float4*)&sW[d*128 + cl];
            a0=fmaf(fd,wv.x,a0); a1=fmaf(fd,wv.y,a1); a2=fmaf(fd,wv.z,a2); a3=fmaf(fd,wv.w,a3);
          }
        }
        float4 o; o.x=a0; o.y=a1; o.z=a2; o.w=a3;
        xp[c >> 2] = o;
        as_ = fmaf(a0, sas[c], fmaf(a1, sas[c+1], fmaf(a2, sas[c+2], fmaf(a3, sas[c+3], as_))));
        ad_ = fmaf(a0, sad[c], fmaf(a1, sad[c+1], fmaf(a2, sad[c+2], fmaf(a3, sad[c+3], ad_))));
      }
      ap[h] = as_; ap[4 + h] = ad_;
    }
  }
}

// ---------------- GAT aggregation: one-pass online softmax, one wave per dst ----------------
__global__ __launch_bounds__(256) void agg_kernel(const float* __restrict__ xh, const float* __restrict__ al,
    const int* __restrict__ rowptr, const int* __restrict__ csr,
    const float* __restrict__ resid, const float* __restrict__ bias,
    float* __restrict__ out){
  int gid = blockIdx.x*256 + threadIdx.x;
  int n = gid >> 6, lane = gid & 63;
  int rs = rowptr[n], re = rowptr[n+1];
  int h = lane >> 4, coff = (lane & 15)*4;
  float ald_h = al[(size_t)n*8 + 4 + h];
  float mx = -3.4e38f, den = 0.f;
  float ax=0.f, ay=0.f, az=0.f, aw=0.f;
  #pragma unroll 2
  for (int e = rs; e < re; e++){
    int s = csr[e];
    float a = al[(size_t)s*8 + h] + ald_h;
    a = a > 0.f ? a : 0.2f*a;                   // leaky_relu
    float nm = fmaxf(mx, a);
    float corr = __expf(mx - nm);
    float ea   = __expf(a - nm);
    mx = nm;
    float4 xv = *(const float4*)(xh + (size_t)s*256 + h*64 + coff);
    den = fmaf(den, corr, ea);
    ax = fmaf(ax, corr, ea*xv.x); ay = fmaf(ay, corr, ea*xv.y);
    az = fmaf(az, corr, ea*xv.z); aw = fmaf(aw, corr, ea*xv.w);
  }
  float rinv = 1.f / (den + 1e-16f);
  float r0 = ax*rinv, r1 = ay*rinv, r2 = az*rinv, r3 = aw*rinv;
  r0 += __shfl_xor(r0, 16, 64); r1 += __shfl_xor(r1, 16, 64);
  r2 += __shfl_xor(r2, 16, 64); r3 += __shfl_xor(r3, 16, 64);
  r0 += __shfl_xor(r0, 32, 64); r1 += __shfl_xor(r1, 32, 64);
  r2 += __shfl_xor(r2, 32, 64); r3 += __shfl_xor(r3, 32, 64);
  if (lane < 16){
    float4 bs = *(const float4*)(bias + coff);
    float4 rv = *(const float4*)(resid + (size_t)n*64 + coff);
    float4 o;
    o.x = r0*0.25f + bs.x + rv.x; o.y = r1*0.25f + bs.y + rv.y;
    o.z = r2*0.25f + bs.z + rv.z; o.w = r3*0.25f + bs.w + rv.w;
    *(float4*)(out + (size_t)n*64 + coff) = o;
  }
}

// ---------------- output MLP: 64->64 elu ->32 elu ->8 ----------------
__global__ __launch_bounds__(256) void mlp_kernel(const float* __restrict__ feat,
    const float* __restrict__ W1, const float* __restrict__ b1,
    const float* __restrict__ W2, const float* __restrict__ b2,
    const float* __restrict__ W3, const float* __restrict__ b3,
    float* __restrict__ out){
  __shared__ float s1[4096], s2[2048], s3[256], t1[64], t2[32], t3[8];
  int t = threadIdx.x;
  for (int i = t; i < 4096; i += 256) s1[i] = W1[i];
  for (int i = t; i < 2048; i += 256) s2[i] = W2[i];
  if (t < 256) s3[t] = W3[t];
  if (t < 64) t1[t] = b1[t];
  if (t < 32) t2[t] = b2[t];
  if (t < 8)  t3[t] = b3[t];
  __syncthreads();
  int n = blockIdx.x*256 + t;
  float4 fv[16];
  const float4* fp = (const float4*)(feat + (size_t)n*64);
  #pragma unroll
  for (int i = 0; i < 16; i++) fv[i] = fp[i];
  float o1[64];
  #pragma unroll 1
  for (int c4 = 0; c4 < 16; c4++){
    float a0=t1[c4*4+0], a1=t1[c4*4+1], a2=t1[c4*4+2], a3=t1[c4*4+3];
    #pragma unroll
    for (int d4 = 0; d4 < 16; d4++){
      float4 fq = fv[d4];
      #pragma unroll
      for (int dd = 0; dd < 4; dd++){
        int d = d4*4 + dd;
        float fd = dd==0?fq.x : dd==1?fq.y : dd==2?fq.z : fq.w;
        float4 wv = *(const float4*)&s1[d*64 + c4*4];
        a0=fmaf(fd,wv.x,a0); a1=fmaf(fd,wv.y,a1); a2=fmaf(fd,wv.z,a2); a3=fmaf(fd,wv.w,a3);
      }
    }
    o1[c4*4+0]=elu_f(a0); o1[c4*4+1]=elu_f(a1); o1[c4*4+2]=elu_f(a2); o1[c4*4+3]=elu_f(a3);
  }
  float o2[32];
  #pragma unroll 1
  for (int c4 = 0; c4 < 8; c4++){
    float a0=t2[c4*4+0], a1=t2[c4*4+1], a2=t2[c4*4+2], a3=t2[c4*4+3];
    #pragma unroll
    for (int d = 0; d < 64; d++){
      float fd = o1[d];
      float4 wv = *(const float4*)&s2[d*32 + c4*4];
      a0=fmaf(fd,wv.x,a0); a1=fmaf(fd,wv.y,a1); a2=fmaf(fd,wv.z,a2); a3=fmaf(fd,wv.w,a3);
    }
    o2[c4*4+0]=elu_f(a0); o2[c4*4+1]=elu_f(a1); o2[c4*4+2]=elu_f(a2); o2[c4*4+3]=elu_f(a3);
  }
  float4* op = (float4*)(out + (size_t)n*8);
  #pragma unroll
  for (int c4 = 0; c4 < 2; c4++){
    float a0=t3[c4*4+0], a1=t3[c4*4+1], a2=t3[c4*4+2], a3=t3[c4*4+3];
    #pragma unroll
    for (int d = 0; d < 32; d++){
      float fd = o2[d];
      float4 wv = *(const float4*)&s3[d*8 + c4*4];
      a0=fmaf(fd,wv.x,a0); a1=fmaf(fd,wv.y,a1); a2=fmaf(fd,wv.z,a2); a3=fmaf(fd,wv.w,a3);
    }
    float4 o; o.x=a0; o.y=a1; o.z=a2; o.w=a3;
    op[c4] = o;
  }
}

extern "C" void kernel_launch(void* const* d_in, const int* in_sizes, int n_in,
                              void* d_out, int out_size, void* d_ws, size_t ws_size,
                              hipStream_t stream){
  (void)n_in; (void)out_size; (void)ws_size;
  const float* x     = (const float*)d_in[0];
  const int*   ei    = (const int*)d_in[2];
  const int    E     = in_sizes[2] / 2;
  const float* encW1 = (const float*)d_in[3];
  const float* encb1 = (const float*)d_in[4];
  const float* encW2 = (const float*)d_in[5];
  const float* encb2 = (const float*)d_in[6];
  const float* convW = (const float*)d_in[7];
  const float* convb = (const float*)d_in[8];
  const float* bng   = (const float*)d_in[9];
  const float* bnb   = (const float*)d_in[10];
  const float* bnm   = (const float*)d_in[11];
  const float* bnv   = (const float*)d_in[12];
  const float* gatW  = (const float*)d_in[13];
  const float* gatas = (const float*)d_in[14];
  const float* gatad = (const float*)d_in[15];
  const float* gatb  = (const float*)d_in[16];
  const float* oW1   = (const float*)d_in[17];
  const float* ob1   = (const float*)d_in[18];
  const float* oW2   = (const float*)d_in[19];
  const float* ob2   = (const float*)d_in[20];
  const float* oW3   = (const float*)d_in[21];
  const float* ob3   = (const float*)d_in[22];

  char* wp = (char*)d_ws;
  auto alloc = [&](size_t bytes)->void*{
    void* p = (void*)wp; wp += (bytes + 255) & ~((size_t)255); return p;
  };
  float* fA     = (float*)alloc((size_t)NTOT*64*4);
  float* fB     = (float*)alloc((size_t)NTOT*64*4);
  float* ubuf   = (float*)alloc((size_t)NTOT*64*4);
  float* vbuf   = (float*)alloc((size_t)NTOT*64*4);
  float* sqb    = (float*)alloc((size_t)NTOT*4);
  int*   idxb   = (int*)  alloc((size_t)NTOT*KNN*4);
  float* xhb    = (float*)alloc((size_t)NTOT*256*4);
  float* alb    = (float*)alloc((size_t)NTOT*8*4);
  int*   degb   = (int*)  alloc((size_t)NTOT*4);
  int*   rowptr = (int*)  alloc((size_t)(NTOT+1)*4);
  int*   cursor = (int*)  alloc((size_t)NTOT*4);
  int*   csr    = (int*)  alloc((size_t)(E+NTOT)*4);
  float* topv   = (float*)alloc((size_t)NTOT*192*4);
  unsigned char* topi = (unsigned char*)alloc((size_t)NTOT*192);

  enc_kernel<<<96,256,0,stream>>>(x, encW1, encb1, encW2, encb2, fA, sqb);
  float* cur = fA; float* nxt = fB;
  for (int l = 0; l < 3; l++){
    disttop_kernel<<<dim3(NTILE,NTILE,NB),256,0,stream>>>(cur, sqb, topv, topi);
    ksel_kernel   <<<NTOT/4,              256,0,stream>>>(topv, topi, cur, sqb, idxb);
    uv_kernel  <<<96,  256,0,stream>>>(cur, convW + (size_t)l*8192, convb + l*64, ubuf, vbuf);
    pool_kernel<<<6144,256,0,stream>>>(ubuf, vbuf, idxb, cur,
                                       bng + l*64, bnb + l*64, bnm + l*64, bnv + l*64, nxt, sqb);
    float* tmp = cur; cur = nxt; nxt = tmp;
  }
  deg_init   <<<96,            256,0,stream>>>(degb);
  deg_hist   <<<(E+255)/256,   256,0,stream>>>(ei, E, degb);
  scan_kernel<<<1,             256,0,stream>>>(degb, rowptr, cursor);
  scatter_kernel<<<(E+NTOT+255)/256,256,0,stream>>>(ei, E, cursor, csr);
  for (int l = 0; l < 2; l++){
    xh_kernel <<<96,  256,0,stream>>>(cur, gatW + (size_t)l*16384, gatas + l*256, gatad + l*256, xhb, alb);
    agg_kernel<<<6144,256,0,stream>>>(xhb, alb, rowptr, csr, cur, gatb + l*64, nxt);
    float* tmp = cur; cur = nxt; nxt = tmp;
  }
  mlp_kernel<<<96,256,0,stream>>>(cur, oW1, ob1, oW2, ob2, oW3, ob3, (float*)d_out);
}

// Round 13
// 1133.804 us; speedup vs baseline: 1.1468x; 1.1350x over previous
//
#include <hip/hip_runtime.h>
#include <math.h>

// Problem constants (match reference)
#define NTOT  24576      // B*N nodes
#define NB    8
#define NPB   3072       // nodes per batch
#define HD    64
#define KNN   20
#define NTILE 24         // NPB/128

__device__ __forceinline__ float elu_f(float x){ return x > 0.f ? x : expm1f(x); }

// ---------------- encoder: x(NT,8) -> elu(elu(x@W1+b1)@W2+b2) (NT,64) + sq ----------------
__global__ __launch_bounds__(256) void enc_kernel(const float* __restrict__ x,
    const float* __restrict__ W1, const float* __restrict__ b1,
    const float* __restrict__ W2, const float* __restrict__ b2,
    float* __restrict__ out, float* __restrict__ sqo){
  __shared__ float sW1[256], sb1[32], sW2[2048], sb2[64];
  int t = threadIdx.x;
  if (t < 256) sW1[t] = W1[t];
  for (int i = t; i < 2048; i += 256) sW2[i] = W2[i];
  if (t < 32) sb1[t] = b1[t];
  if (t < 64) sb2[t] = b2[t];
  __syncthreads();
  int n = blockIdx.x*256 + t;
  const float4* xp = (const float4*)(x + (size_t)n*8);
  float4 x0 = xp[0], x1 = xp[1];
  float xi[8] = {x0.x,x0.y,x0.z,x0.w,x1.x,x1.y,x1.z,x1.w};
  float h1[32];
  #pragma unroll
  for (int j = 0; j < 32; j++){
    float a = sb1[j];
    #pragma unroll
    for (int d = 0; d < 8; d++) a = fmaf(xi[d], sW1[d*32+j], a);
    h1[j] = elu_f(a);
  }
  float4* op = (float4*)(out + (size_t)n*64);
  float ssum = 0.f;
  #pragma unroll
  for (int c4 = 0; c4 < 16; c4++){
    float a0 = sb2[c4*4+0], a1 = sb2[c4*4+1], a2 = sb2[c4*4+2], a3 = sb2[c4*4+3];
    #pragma unroll
    for (int d = 0; d < 32; d++){
      float hd = h1[d];
      float4 wv = *(const float4*)&sW2[d*64 + c4*4];
      a0 = fmaf(hd, wv.x, a0); a1 = fmaf(hd, wv.y, a1);
      a2 = fmaf(hd, wv.z, a2); a3 = fmaf(hd, wv.w, a3);
    }
    float4 o; o.x=elu_f(a0); o.y=elu_f(a1); o.z=elu_f(a2); o.w=elu_f(a3);
    ssum = fmaf(o.x,o.x,ssum); ssum = fmaf(o.y,o.y,ssum);
    ssum = fmaf(o.z,o.z,ssum); ssum = fmaf(o.w,o.w,ssum);
    op[c4] = o;
  }
  sqo[n] = ssum;
}

#define CE(va,ia,vb,ib) { bool sw_ = (vb) < (va); float t1_ = sw_?(vb):(va); float t2_ = sw_?(va):(vb); int t3_ = sw_?(ib):(ia); int t4_ = sw_?(ia):(ib); (va)=t1_; (vb)=t2_; (ia)=t3_; (ib)=t4_; }

// ---------------- fused distance GEMM + per-32-group top-3 (K-split depth 16) ----------------
// grid = dim3(24, 24, NB). Block: 128q x 128c tile, 8x8 acc per thread.
// Summaries (SoA per query): mins[96] | 2nds[96] | 3rds[96] (+ u8 idx each).
// Per row: branchless top-3 insert over the thread's 8 cands, then 2-level
// shfl_xor(1,2) sorted-3 merge across the 4 lanes of the 32-cand group.
__global__ __launch_bounds__(256) void disttop_kernel(const float* __restrict__ feat,
    const float* __restrict__ sqn, float* __restrict__ topv, unsigned char* __restrict__ topi){
  __shared__ float As[16][128];
  __shared__ float Bs[16][128];
  int b  = blockIdx.z;
  int m0 = blockIdx.x * 128;
  int q0 = blockIdx.y * 128;
  const float* fb = feat + (size_t)b*NPB*HD;
  int t = threadIdx.x;
  int tx = t & 15, ty = t >> 4;
  float acc[8][8];
  #pragma unroll
  for (int i = 0; i < 8; i++)
    #pragma unroll
    for (int j = 0; j < 8; j++) acc[i][j] = 0.f;
  #pragma unroll 1
  for (int stage = 0; stage < 4; stage++){
    if (stage) __syncthreads();
    {
      int r = t >> 1, dc = (t & 1) * 8;
      const float4* pa = (const float4*)(fb + (size_t)(q0 + r)*HD + stage*16 + dc);
      const float4* pb = (const float4*)(fb + (size_t)(m0 + r)*HD + stage*16 + dc);
      #pragma unroll
      for (int i = 0; i < 2; i++){
        float4 va = pa[i], vb = pb[i];
        int d = dc + i*4;
        As[d][r]=va.x; As[d+1][r]=va.y; As[d+2][r]=va.z; As[d+3][r]=va.w;
        Bs[d][r]=vb.x; Bs[d+1][r]=vb.y; Bs[d+2][r]=vb.z; Bs[d+3][r]=vb.w;
      }
    }
    __syncthreads();
    #pragma unroll 2
    for (int d = 0; d < 16; d++){
      float af[8], bf[8];
      *(float4*)&af[0] = *(const float4*)&As[d][ty*8];
      *(float4*)&af[4] = *(const float4*)&As[d][ty*8+4];
      *(float4*)&bf[0] = *(const float4*)&Bs[d][tx*8];
      *(float4*)&bf[4] = *(const float4*)&Bs[d][tx*8+4];
      #pragma unroll
      for (int i = 0; i < 8; i++)
        #pragma unroll
        for (int j = 0; j < 8; j++)
          acc[i][j] = fmaf(af[i], bf[j], acc[i][j]);
    }
  }
  float sqv[8];
  {
    const float4* sp = (const float4*)(sqn + (size_t)b*NPB + m0 + tx*8);
    float4 sq0 = sp[0], sq1 = sp[1];
    sqv[0]=sq0.x; sqv[1]=sq0.y; sqv[2]=sq0.z; sqv[3]=sq0.w;
    sqv[4]=sq1.x; sqv[5]=sq1.y; sqv[6]=sq1.z; sqv[7]=sq1.w;
  }
  const float INF = 3.4e38f;
  #pragma unroll
  for (int i = 0; i < 8; i++){
    int qg = q0 + ty*8 + i;        // in-batch query index
    int cex = qg - m0;             // diagonal local cand (may be out of range)
    float s0=INF, s1=INF, s2=INF;
    int i0=0, i1=0, i2=0;
    #pragma unroll
    for (int j = 0; j < 8; j++){
      int c = tx*8 + j;
      float v = fmaf(-2.f, acc[i][j], sqv[j]);
      if (c == cex) v = INF;
      bool l2 = v < s2, l1 = v < s1, l0 = v < s0;
      s2 = l1 ? s1 : (l2 ? v : s2);  i2 = l1 ? i1 : (l2 ? c : i2);
      s1 = l0 ? s0 : (l1 ? v : s1);  i1 = l0 ? i0 : (l1 ? c : i1);
      s0 = l0 ? v : s0;              i0 = l0 ? c : i0;
    }
    // 2-level merge of sorted-3 lists across the 4 lanes of the 32-cand group:
    // lowest-3 of union = {min(a0,b2),min(a1,b1),min(a2,b0)}, then 3-sort.
    #pragma unroll
    for (int off = 1; off < 4; off <<= 1){
      float b0 = __shfl_xor(s0,off,64), b1 = __shfl_xor(s1,off,64), b2 = __shfl_xor(s2,off,64);
      int  bj0 = __shfl_xor(i0,off,64), bj1 = __shfl_xor(i1,off,64), bj2 = __shfl_xor(i2,off,64);
      bool c0 = s0 <= b2; float w0 = c0 ? s0 : b2; int x0 = c0 ? i0 : bj2;
      bool c1 = s1 <= b1; float w1 = c1 ? s1 : b1; int x1 = c1 ? i1 : bj1;
      bool c2 = s2 <= b0; float w2 = c2 ? s2 : b0; int x2 = c2 ? i2 : bj0;
      CE(w0,x0,w1,x1); CE(w0,x0,w2,x2); CE(w1,x1,w2,x2);
      s0=w0; s1=w1; s2=w2; i0=x0; i1=x1; i2=x2;
    }
    if ((tx & 3) == 0){
      size_t g = (size_t)b*NPB + qg;
      int e = blockIdx.x*4 + (tx >> 2);        // global group id 0..95
      float* vq = topv + g*288;
      unsigned char* iq = topi + g*288;
      vq[e] = s0; vq[96+e] = s1; vq[192+e] = s2;
      iq[e] = (unsigned char)i0; iq[96+e] = (unsigned char)i1; iq[192+e] = (unsigned char)i2;
    }
  }
}

// ---------------- exact top-20 from per-group top-3 summaries ----------------
// One wave per query. T = 20th smallest of the 64 collapsed group minima
// (actual row values => T >= v20). Group clean iff stored 3rd > T: then all
// its <=T values are the stored 1st/2nd (collected). Flagged groups (3rd<=T)
// are recomputed over their 32 cands with the bitwise-identical fma chain.
// Lex bitonic on (monotone_f32<<32|idx) -> exact top-20 (top_k tie-break).
__global__ __launch_bounds__(256) void ksel_kernel(const float* __restrict__ topv,
    const unsigned char* __restrict__ topi, const float* __restrict__ feat,
    const float* __restrict__ sqn, int* __restrict__ idxout){
  __shared__ float cvs[4][72];
  __shared__ int   cxs[4][72];
  int wid = threadIdx.x >> 6, lane = threadIdx.x & 63;
  int g = blockIdx.x*4 + wid;
  int b = g / NPB;
  int ql = g - b*NPB;
  const float INF = 3.4e38f;
  const float* tv = topv + (size_t)g*288;
  const unsigned char* ti = topi + (size_t)g*288;
  // slot a: group = lane; slot b: group = 64+lane (lane<32)
  float ma = tv[lane],      sa = tv[96+lane],  ta = tv[192+lane];
  int   ja = ti[lane],      ka = ti[96+lane];
  float mb = INF, sb = INF, tb = INF;
  int   jb = 0,  kb = 0;
  if (lane < 32){
    mb = tv[64+lane];  sb = tv[160+lane];  tb = tv[256+lane];
    jb = ti[64+lane];  kb = ti[160+lane];
  }
  // threshold: 20th smallest of 64 collapsed group minima
  float T;
  {
    float v = fminf(ma, mb);
    #pragma unroll
    for (int k = 2; k <= 64; k <<= 1){
      #pragma unroll
      for (int j = k >> 1; j > 0; j >>= 1){
        float o = __shfl_xor(v, j, 64);
        bool up    = ((lane & k) == 0);
        bool lower = ((lane & j) == 0);
        float mn = fminf(v, o), mx = fmaxf(v, o);
        v = (lower == up) ? mn : mx;
      }
    }
    T = __shfl(v, 19, 64);
  }
  bool cleanA = (ta > T);
  bool cleanB = (tb > T);          // lanes>=32 have tb=INF -> clean, never fire
  // collect stored qualifiers from clean groups
  float* cv = cvs[wid]; int* cx = cxs[wid];
  int base = 0;
  {
    bool f = cleanA && (ma <= T);
    unsigned long long mk = __ballot(f);
    int pos = (int)__popcll(mk & ((1ull<<lane)-1ull));
    if (f && pos < 64){ cv[pos] = ma; cx[pos] = (lane>>2)*128 + ja; }
    base = (int)__popcll(mk);
    f = cleanA && (sa <= T);
    mk = __ballot(f);
    pos = base + (int)__popcll(mk & ((1ull<<lane)-1ull));
    if (f && pos < 64){ cv[pos] = sa; cx[pos] = (lane>>2)*128 + ka; }
    base += (int)__popcll(mk);
    f = (lane < 32) && cleanB && (mb <= T);
    mk = __ballot(f);
    pos = base + (int)__popcll(mk & ((1ull<<lane)-1ull));
    if (f && pos < 64){ cv[pos] = mb; cx[pos] = ((64+lane)>>2)*128 + jb; }
    base += (int)__popcll(mk);
    f = (lane < 32) && cleanB && (sb <= T);
    mk = __ballot(f);
    pos = base + (int)__popcll(mk & ((1ull<<lane)-1ull));
    if (f && pos < 64){ cv[pos] = sb; cx[pos] = ((64+lane)>>2)*128 + kb; }
    base += (int)__popcll(mk);
  }
  // flagged groups: 3rd <= T -> rescan all 32 cands
  unsigned long long fa = __ballot(!cleanA);
  unsigned long long fbm = __ballot((lane < 32) && !cleanB);
  const float* fqp = feat + (size_t)g*HD;
  #pragma unroll 1
  for (int w = 0; w < 2; w++){
    unsigned long long fm = (w==0) ? fa : fbm;
    int gofs = (w==0) ? 0 : 64;
    while (fm){
      int p = __ffsll((unsigned long long)fm) - 1; fm &= fm - 1;
      int gg = gofs + p;                   // global group id 0..95
      int mbase = (gg >> 2)*128 + (gg & 3)*32;
      bool fire = false; float s = 0.f;
      if (lane < 32){
        int m = mbase + lane;
        const float* fmp = feat + (size_t)(b*NPB + m)*HD;
        float acc = 0.f;
        #pragma unroll
        for (int d4 = 0; d4 < 16; d4++){
          float4 fq4 = *(const float4*)(fqp + d4*4);
          float4 fm4 = *(const float4*)(fmp + d4*4);
          acc = fmaf(fq4.x, fm4.x, acc);
          acc = fmaf(fq4.y, fm4.y, acc);
          acc = fmaf(fq4.z, fm4.z, acc);
          acc = fmaf(fq4.w, fm4.w, acc);
        }
        s = fmaf(-2.f, acc, sqn[(size_t)b*NPB + m]);
        fire = (m != ql) && (s <= T);
      }
      unsigned long long mk2 = __ballot(fire);
      int p2 = base + (int)__popcll(mk2 & ((1ull<<lane)-1ull));
      if (fire && p2 < 64){ cv[p2] = s; cx[p2] = mbase + lane; }
      base += (int)__popcll(mk2);
    }
  }
  if (base <= 64){
    unsigned long long key;
    if (lane < base){
      unsigned int ku = __float_as_uint(cv[lane]);
      ku ^= (unsigned)(((int)ku) >> 31) | 0x80000000u;
      key = ((unsigned long long)ku << 32) | (unsigned int)cx[lane];
    } else key = ~0ull;
    #pragma unroll
    for (int k = 2; k <= 64; k <<= 1){
      #pragma unroll
      for (int j = k >> 1; j > 0; j >>= 1){
        unsigned long long o = __shfl_xor(key, j, 64);
        bool up    = ((lane & k) == 0);
        bool lower = ((lane & j) == 0);
        unsigned long long mn = key < o ? key : o;
        unsigned long long mx = key < o ? o : key;
        key = (lower == up) ? mn : mx;
      }
    }
    if (lane < KNN)
      idxout[(size_t)g*KNN + lane] = b*NPB + (int)(unsigned int)(key & 0xffffffffu);
  } else {
    // degenerate-tie fallback: full recompute, per-lane insert + 20-round merge
    float dl[KNN]; int il[KNN];
    #pragma unroll
    for (int k = 0; k < KNN; k++){ dl[k] = INF; il[k] = 0x7fffffff; }
    #pragma unroll 1
    for (int j = 0; j < 48; j++){
      int m = j*64 + lane;
      if (m == ql) continue;
      const float* fmp = feat + (size_t)(b*NPB + m)*HD;
      float acc = 0.f;
      for (int d4 = 0; d4 < 16; d4++){
        float4 fq4 = *(const float4*)(fqp + d4*4);
        float4 fm4 = *(const float4*)(fmp + d4*4);
        acc = fmaf(fq4.x, fm4.x, acc);
        acc = fmaf(fq4.y, fm4.y, acc);
        acc = fmaf(fq4.z, fm4.z, acc);
        acc = fmaf(fq4.w, fm4.w, acc);
      }
      float s = fmaf(-2.f, acc, sqn[(size_t)b*NPB + m]);
      if (s < dl[KNN-1]){
        #pragma unroll
        for (int k = KNN-1; k >= 1; k--){
          bool c1 = s < dl[k-1];
          bool c0 = s < dl[k];
          dl[k] = c1 ? dl[k-1] : (c0 ? s : dl[k]);
          il[k] = c1 ? il[k-1] : (c0 ? m : il[k]);
        }
        if (s < dl[0]){ dl[0] = s; il[0] = m; }
      }
    }
    int res = 0;
    #pragma unroll 1
    for (int r = 0; r < KNN; r++){
      float d = dl[0]; int i = il[0];
      #pragma unroll
      for (int off = 1; off < 64; off <<= 1){
        float od = __shfl_xor(d, off, 64);
        int   oi = __shfl_xor(i, off, 64);
        if (od < d || (od == d && oi < i)){ d = od; i = oi; }
      }
      if (lane == r) res = i;
      if (il[0] == i){
        #pragma unroll
        for (int k = 0; k < KNN-1; k++){ dl[k] = dl[k+1]; il[k] = il[k+1]; }
        dl[KNN-1] = INF; il[KNN-1] = 0x7fffffff;
      }
    }
    if (lane < KNN) idxout[(size_t)g*KNN + lane] = b*NPB + res;
  }
}

// ---------------- edge-conv factorization: u = x@(Wt-Wb)+b, v = x@Wb ----------------
__global__ __launch_bounds__(256) void uv_kernel(const float* __restrict__ feat,
    const float* __restrict__ W, const float* __restrict__ cb,
    float* __restrict__ u, float* __restrict__ v){
  __shared__ float sW[128*64];
  int t = threadIdx.x;
  for (int i = t; i < 8192; i += 256) sW[i] = W[i];
  __syncthreads();
  int n = blockIdx.x*256 + t;
  float4 fv[16];
  const float4* fp = (const float4*)(feat + (size_t)n*64);
  #pragma unroll
  for (int i = 0; i < 16; i++) fv[i] = fp[i];
  float4* up = (float4*)(u + (size_t)n*64);
  float4* vp = (float4*)(v + (size_t)n*64);
  #pragma unroll 1
  for (int c4 = 0; c4 < 16; c4++){
    float ua0=0,ua1=0,ua2=0,ua3=0, vb0=0,vb1=0,vb2=0,vb3=0;
    #pragma unroll
    for (int d4 = 0; d4 < 16; d4++){
      float4 fq = fv[d4];
      #pragma unroll
      for (int dd = 0; dd < 4; dd++){
        int d = d4*4 + dd;
        float fd = dd==0?fq.x : dd==1?fq.y : dd==2?fq.z : fq.w;
        float4 wt = *(const float4*)&sW[d*64 + c4*4];
        float4 wb = *(const float4*)&sW[(64+d)*64 + c4*4];
        ua0=fmaf(fd,wt.x,ua0); ua1=fmaf(fd,wt.y,ua1); ua2=fmaf(fd,wt.z,ua2); ua3=fmaf(fd,wt.w,ua3);
        vb0=fmaf(fd,wb.x,vb0); vb1=fmaf(fd,wb.y,vb1); vb2=fmaf(fd,wb.z,vb2); vb3=fmaf(fd,wb.w,vb3);
      }
    }
    float4 cbv = *(const float4*)&cb[c4*4];
    float4 uo, vo;
    uo.x = cbv.x + ua0 - vb0; uo.y = cbv.y + ua1 - vb1;
    uo.z = cbv.z + ua2 - vb2; uo.w = cbv.w + ua3 - vb3;
    vo.x = vb0; vo.y = vb1; vo.z = vb2; vo.w = vb3;
    up[c4] = uo; vp[c4] = vo;
  }
}

// ---------------- max-pool + BN + residual + sq of output (one wave per node) ----------------
__global__ __launch_bounds__(256) void pool_kernel(const float* __restrict__ u, const float* __restrict__ v,
    const int* __restrict__ idx, const float* __restrict__ resid,
    const float* __restrict__ bg, const float* __restrict__ bb,
    const float* __restrict__ bm, const float* __restrict__ bv,
    float* __restrict__ out, float* __restrict__ sqo){
  int gid = blockIdx.x*256 + threadIdx.x;
  int n = gid >> 6, lane = gid & 63;
  float uc = u[(size_t)n*64 + lane];
  float scale = bg[lane] / sqrtf(bv[lane] + 1e-5f);
  float bias  = bb[lane] - bm[lane]*scale;
  const int* ip = idx + (size_t)n*KNN;
  float acc = -3.4e38f;
  #pragma unroll 4
  for (int k = 0; k < KNN; k++){
    int j = ip[k];
    float s = uc + v[(size_t)j*64 + lane];
    acc = fmaxf(acc, fmaf(elu_f(s), scale, bias));
  }
  float val = acc + resid[(size_t)n*64 + lane];
  out[(size_t)n*64 + lane] = val;
  float ss = val*val;
  #pragma unroll
  for (int off = 1; off < 64; off <<= 1) ss += __shfl_xor(ss, off, 64);
  if (lane == 0) sqo[n] = ss;
}

// ---------------- CSR build over dst (edges + self loops) ----------------
__global__ void deg_init(int* deg){ int i = blockIdx.x*256 + threadIdx.x; if (i < NTOT) deg[i] = 1; }
__global__ void deg_hist(const int* __restrict__ ei, int E, int* deg){
  int i = blockIdx.x*256 + threadIdx.x; if (i < E) atomicAdd(&deg[ei[E + i]], 1);
}
__global__ void scan_kernel(const int* __restrict__ deg, int* __restrict__ rowptr, int* __restrict__ cursor){
  __shared__ int part[256];
  int t = threadIdx.x;
  int base = t*96;
  int s = 0;
  for (int i = 0; i < 96; i++) s += deg[base + i];
  part[t] = s;
  __syncthreads();
  for (int off = 1; off < 256; off <<= 1){
    int xv = (t >= off) ? part[t - off] : 0;
    __syncthreads();
    part[t] += xv;
    __syncthreads();
  }
  int run = part[t] - s;
  for (int i = 0; i < 96; i++){
    rowptr[base + i] = run; cursor[base + i] = run; run += deg[base + i];
  }
  if (t == 255) rowptr[NTOT] = run;
}
__global__ void scatter_kernel(const int* __restrict__ ei, int E, int* cursor, int* __restrict__ csr){
  int i = blockIdx.x*256 + threadIdx.x;
  if (i >= E + NTOT) return;
  int s, d;
  if (i < E){ s = ei[i]; d = ei[E + i]; } else { s = i - E; d = s; }
  int pos = atomicAdd(&cursor[d], 1);
  csr[pos] = s;
}

// ---------------- GAT: xh = x@W (NT,256), al_s/al_d per head ----------------
__global__ __launch_bounds__(256) void xh_kernel(const float* __restrict__ feat,
    const float* __restrict__ W, const float* __restrict__ asrc, const float* __restrict__ adst,
    float* __restrict__ xh, float* __restrict__ al){
  __shared__ float sW[64*128];
  __shared__ float sas[256], sad[256];
  int t = threadIdx.x;
  if (t < 256){ sas[t] = asrc[t]; sad[t] = adst[t]; }
  int n = blockIdx.x*256 + t;
  float4 fv[16];
  const float4* fp = (const float4*)(feat + (size_t)n*64);
  #pragma unroll
  for (int i = 0; i < 16; i++) fv[i] = fp[i];
  float4* xp = (float4*)(xh + (size_t)n*256);
  float* ap = al + (size_t)n*8;
  #pragma unroll 1
  for (int half = 0; half < 2; half++){
    __syncthreads();
    for (int i = t; i < 8192; i += 256){
      int d = i >> 7, c = i & 127;
      sW[i] = W[d*256 + half*128 + c];
    }
    __syncthreads();
    #pragma unroll 1
    for (int hh = 0; hh < 2; hh++){
      int h = half*2 + hh;
      float as_ = 0.f, ad_ = 0.f;
      #pragma unroll 1
      for (int cc = 0; cc < 64; cc += 4){
        int c  = h*64 + cc;
        int cl = hh*64 + cc;
        float a0=0,a1=0,a2=0,a3=0;
        #pragma unroll
        for (int d4 = 0; d4 < 16; d4++){
          float4 fq = fv[d4];
          #pragma unroll
          for (int dd = 0; dd < 4; dd++){
            int d = d4*4 + dd;
            float fd = dd==0?fq.x : dd==1?fq.y : dd==2?fq.z : fq.w;
            float4 wv = *(const float4*)&sW[d*128 + cl];
            a0=fmaf(fd,wv.x,a0); a1=fmaf(fd,wv.y,a1); a2=fmaf(fd,wv.z,a2); a3=fmaf(fd,wv.w,a3);
          }
        }
        float4 o; o.x=a0; o.y=a1; o.z=a2; o.w=a3;
        xp[c >> 2] = o;
        as_ = fmaf(a0, sas[c], fmaf(a1, sas[c+1], fmaf(a2, sas[c+2], fmaf(a3, sas[c+3], as_))));
        ad_ = fmaf(a0, sad[c], fmaf(a1, sad[c+1], fmaf(a2, sad[c+2], fmaf(a3, sad[c+3], ad_))));
      }
      ap[h] = as_; ap[4 + h] = ad_;
    }
  }
}

// ---------------- GAT aggregation: one-pass online softmax, one wave per dst ----------------
__global__ __launch_bounds__(256) void agg_kernel(const float* __restrict__ xh, const float* __restrict__ al,
    const int* __restrict__ rowptr, const int* __restrict__ csr,
    const float* __restrict__ resid, const float* __restrict__ bias,
    float* __restrict__ out){
  int gid = blockIdx.x*256 + threadIdx.x;
  int n = gid >> 6, lane = gid & 63;
  int rs = rowptr[n], re = rowptr[n+1];
  int h = lane >> 4, coff = (lane & 15)*4;
  float ald_h = al[(size_t)n*8 + 4 + h];
  float mx = -3.4e38f, den = 0.f;
  float ax=0.f, ay=0.f, az=0.f, aw=0.f;
  #pragma unroll 2
  for (int e = rs; e < re; e++){
    int s = csr[e];
    float a = al[(size_t)s*8 + h] + ald_h;
    a = a > 0.f ? a : 0.2f*a;                   // leaky_relu
    float nm = fmaxf(mx, a);
    float corr = __expf(mx - nm);
    float ea   = __expf(a - nm);
    mx = nm;
    float4 xv = *(const float4*)(xh + (size_t)s*256 + h*64 + coff);
    den = fmaf(den, corr, ea);
    ax = fmaf(ax, corr, ea*xv.x); ay = fmaf(ay, corr, ea*xv.y);
    az = fmaf(az, corr, ea*xv.z); aw = fmaf(aw, corr, ea*xv.w);
  }
  float rinv = 1.f / (den + 1e-16f);
  float r0 = ax*rinv, r1 = ay*rinv, r2 = az*rinv, r3 = aw*rinv;
  r0 += __shfl_xor(r0, 16, 64); r1 += __shfl_xor(r1, 16, 64);
  r2 += __shfl_xor(r2, 16, 64); r3 += __shfl_xor(r3, 16, 64);
  r0 += __shfl_xor(r0, 32, 64); r1 += __shfl_xor(r1, 32, 64);
  r2 += __shfl_xor(r2, 32, 64); r3 += __shfl_xor(r3, 32, 64);
  if (lane < 16){
    float4 bs = *(const float4*)(bias + coff);
    float4 rv = *(const float4*)(resid + (size_t)n*64 + coff);
    float4 o;
    o.x = r0*0.25f + bs.x + rv.x; o.y = r1*0.25f + bs.y + rv.y;
    o.z = r2*0.25f + bs.z + rv.z; o.w = r3*0.25f + bs.w + rv.w;
    *(float4*)(out + (size_t)n*64 + coff) = o;
  }
}

// ---------------- output MLP: 64->64 elu ->32 elu ->8 ----------------
__global__ __launch_bounds__(256) void mlp_kernel(const float* __restrict__ feat,
    const float* __restrict__ W1, const float* __restrict__ b1,
    const float* __restrict__ W2, const float* __restrict__ b2,
    const float* __restrict__ W3, const float* __restrict__ b3,
    float* __restrict__ out){
  __shared__ float s1[4096], s2[2048], s3[256], t1[64], t2[32], t3[8];
  int t = threadIdx.x;
  for (int i = t; i < 4096; i += 256) s1[i] = W1[i];
  for (int i = t; i < 2048; i += 256) s2[i] = W2[i];
  if (t < 256) s3[t] = W3[t];
  if (t < 64) t1[t] = b1[t];
  if (t < 32) t2[t] = b2[t];
  if (t < 8)  t3[t] = b3[t];
  __syncthreads();
  int n = blockIdx.x*256 + t;
  float4 fv[16];
  const float4* fp = (const float4*)(feat + (size_t)n*64);
  #pragma unroll
  for (int i = 0; i < 16; i++) fv[i] = fp[i];
  float o1[64];
  #pragma unroll 1
  for (int c4 = 0; c4 < 16; c4++){
    float a0=t1[c4*4+0], a1=t1[c4*4+1], a2=t1[c4*4+2], a3=t1[c4*4+3];
    #pragma unroll
    for (int d4 = 0; d4 < 16; d4++){
      float4 fq = fv[d4];
      #pragma unroll
      for (int dd = 0; dd < 4; dd++){
        int d = d4*4 + dd;
        float fd = dd==0?fq.x : dd==1?fq.y : dd==2?fq.z : fq.w;
        float4 wv = *(const float4*)&s1[d*64 + c4*4];
        a0=fmaf(fd,wv.x,a0); a1=fmaf(fd,wv.y,a1); a2=fmaf(fd,wv.z,a2); a3=fmaf(fd,wv.w,a3);
      }
    }
    o1[c4*4+0]=elu_f(a0); o1[c4*4+1]=elu_f(a1); o1[c4*4+2]=elu_f(a2); o1[c4*4+3]=elu_f(a3);
  }
  float o2[32];
  #pragma unroll 1
  for (int c4 = 0; c4 < 8; c4++){
    float a0=t2[c4*4+0], a1=t2[c4*4+1], a2=t2[c4*4+2], a3=t2[c4*4+3];
    #pragma unroll
    for (int d = 0; d < 64; d++){
      float fd = o1[d];
      float4 wv = *(const float4*)&s2[d*32 + c4*4];
      a0=fmaf(fd,wv.x,a0); a1=fmaf(fd,wv.y,a1); a2=fmaf(fd,wv.z,a2); a3=fmaf(fd,wv.w,a3);
    }
    o2[c4*4+0]=elu_f(a0); o2[c4*4+1]=elu_f(a1); o2[c4*4+2]=elu_f(a2); o2[c4*4+3]=elu_f(a3);
  }
  float4* op = (float4*)(out + (size_t)n*8);
  #pragma unroll
  for (int c4 = 0; c4 < 2; c4++){
    float a0=t3[c4*4+0], a1=t3[c4*4+1], a2=t3[c4*4+2], a3=t3[c4*4+3];
    #pragma unroll
    for (int d = 0; d < 32; d++){
      float fd = o2[d];
      float4 wv = *(const float4*)&s3[d*8 + c4*4];
      a0=fmaf(fd,wv.x,a0); a1=fmaf(fd,wv.y,a1); a2=fmaf(fd,wv.z,a2); a3=fmaf(fd,wv.w,a3);
    }
    float4 o; o.x=a0; o.y=a1; o.z=a2; o.w=a3;
    op[c4] = o;
  }
}

extern "C" void kernel_launch(void* const* d_in, const int* in_sizes, int n_in,
                              void* d_out, int out_size, void* d_ws, size_t ws_size,
                              hipStream_t stream){
  (void)n_in; (void)out_size; (void)ws_size;
  const float* x     = (const float*)d_in[0];
  const int*   ei    = (const int*)d_in[2];
  const int    E     = in_sizes[2] / 2;
  const float* encW1 = (const float*)d_in[3];
  const float* encb1 = (const float*)d_in[4];
  const float* encW2 = (const float*)d_in[5];
  const float* encb2 = (const float*)d_in[6];
  const float* convW = (const float*)d_in[7];
  const float* convb = (const float*)d_in[8];
  const float* bng   = (const float*)d_in[9];
  const float* bnb   = (const float*)d_in[10];
  const float* bnm   = (const float*)d_in[11];
  const float* bnv   = (const float*)d_in[12];
  const float* gatW  = (const float*)d_in[13];
  const float* gatas = (const float*)d_in[14];
  const float* gatad = (const float*)d_in[15];
  const float* gatb  = (const float*)d_in[16];
  const float* oW1   = (const float*)d_in[17];
  const float* ob1   = (const float*)d_in[18];
  const float* oW2   = (const float*)d_in[19];
  const float* ob2   = (const float*)d_in[20];
  const float* oW3   = (const float*)d_in[21];
  const float* ob3   = (const float*)d_in[22];

  char* wp = (char*)d_ws;
  auto alloc = [&](size_t bytes)->void*{
    void* p = (void*)wp; wp += (bytes + 255) & ~((size_t)255); return p;
  };
  float* fA     = (float*)alloc((size_t)NTOT*64*4);
  float* fB     = (float*)alloc((size_t)NTOT*64*4);
  float* ubuf   = (float*)alloc((size_t)NTOT*64*4);
  float* vbuf   = (float*)alloc((size_t)NTOT*64*4);
  float* sqb    = (float*)alloc((size_t)NTOT*4);
  int*   idxb   = (int*)  alloc((size_t)NTOT*KNN*4);
  float* xhb    = (float*)alloc((size_t)NTOT*256*4);
  float* alb    = (float*)alloc((size_t)NTOT*8*4);
  int*   degb   = (int*)  alloc((size_t)NTOT*4);
  int*   rowptr = (int*)  alloc((size_t)(NTOT+1)*4);
  int*   cursor = (int*)  alloc((size_t)NTOT*4);
  int*   csr    = (int*)  alloc((size_t)(E+NTOT)*4);
  float* topv   = (float*)alloc((size_t)NTOT*288*4);
  unsigned char* topi = (unsigned char*)alloc((size_t)NTOT*288);

  enc_kernel<<<96,256,0,stream>>>(x, encW1, encb1, encW2, encb2, fA, sqb);
  float* cur = fA; float* nxt = fB;
  for (int l = 0; l < 3; l++){
    disttop_kernel<<<dim3(NTILE,NTILE,NB),256,0,stream>>>(cur, sqb, topv, topi);
    ksel_kernel   <<<NTOT/4,              256,0,stream>>>(topv, topi, cur, sqb, idxb);
    uv_kernel  <<<96,  256,0,stream>>>(cur, convW + (size_t)l*8192, convb + l*64, ubuf, vbuf);
    pool_kernel<<<6144,256,0,stream>>>(ubuf, vbuf, idxb, cur,
                                       bng + l*64, bnb + l*64, bnm + l*64, bnv + l*64, nxt, sqb);
    float* tmp = cur; cur = nxt; nxt = tmp;
  }
  deg_init   <<<96,            256,0,stream>>>(degb);
  deg_hist   <<<(E+255)/256,   256,0,stream>>>(ei, E, degb);
  scan_kernel<<<1,             256,0,stream>>>(degb, rowptr, cursor);
  scatter_kernel<<<(E+NTOT+255)/256,256,0,stream>>>(ei, E, cursor, csr);
  for (int l = 0; l < 2; l++){
    xh_kernel <<<96,  256,0,stream>>>(cur, gatW + (size_t)l*16384, gatas + l*256, gatad + l*256, xhb, alb);
    agg_kernel<<<6144,256,0,stream>>>(xhb, alb, rowptr, csr, cur, gatb + l*64, nxt);
    float* tmp = cur; cur = nxt; nxt = tmp;
  }
  mlp_kernel<<<96,256,0,stream>>>(cur, oW1, ob1, oW2, ob2, oW3, ob3, (float*)d_out);
}

// Round 14
// 1126.312 us; speedup vs baseline: 1.1544x; 1.0067x over previous
//
#include <hip/hip_runtime.h>
#include <math.h>

// Problem constants (match reference)
#define NTOT  24576      // B*N nodes
#define NB    8
#define NPB   3072       // nodes per batch
#define HD    64
#define KNN   20
#define NTILE 24         // NPB/128

__device__ __forceinline__ float elu_f(float x){ return x > 0.f ? x : expm1f(x); }

// ---------------- encoder: x(NT,8) -> elu(elu(x@W1+b1)@W2+b2) (NT,64) + sq ----------------
__global__ __launch_bounds__(256) void enc_kernel(const float* __restrict__ x,
    const float* __restrict__ W1, const float* __restrict__ b1,
    const float* __restrict__ W2, const float* __restrict__ b2,
    float* __restrict__ out, float* __restrict__ sqo){
  __shared__ float sW1[256], sb1[32], sW2[2048], sb2[64];
  int t = threadIdx.x;
  if (t < 256) sW1[t] = W1[t];
  for (int i = t; i < 2048; i += 256) sW2[i] = W2[i];
  if (t < 32) sb1[t] = b1[t];
  if (t < 64) sb2[t] = b2[t];
  __syncthreads();
  int n = blockIdx.x*256 + t;
  const float4* xp = (const float4*)(x + (size_t)n*8);
  float4 x0 = xp[0], x1 = xp[1];
  float xi[8] = {x0.x,x0.y,x0.z,x0.w,x1.x,x1.y,x1.z,x1.w};
  float h1[32];
  #pragma unroll
  for (int j = 0; j < 32; j++){
    float a = sb1[j];
    #pragma unroll
    for (int d = 0; d < 8; d++) a = fmaf(xi[d], sW1[d*32+j], a);
    h1[j] = elu_f(a);
  }
  float4* op = (float4*)(out + (size_t)n*64);
  float ssum = 0.f;
  #pragma unroll
  for (int c4 = 0; c4 < 16; c4++){
    float a0 = sb2[c4*4+0], a1 = sb2[c4*4+1], a2 = sb2[c4*4+2], a3 = sb2[c4*4+3];
    #pragma unroll
    for (int d = 0; d < 32; d++){
      float hd = h1[d];
      float4 wv = *(const float4*)&sW2[d*64 + c4*4];
      a0 = fmaf(hd, wv.x, a0); a1 = fmaf(hd, wv.y, a1);
      a2 = fmaf(hd, wv.z, a2); a3 = fmaf(hd, wv.w, a3);
    }
    float4 o; o.x=elu_f(a0); o.y=elu_f(a1); o.z=elu_f(a2); o.w=elu_f(a3);
    ssum = fmaf(o.x,o.x,ssum); ssum = fmaf(o.y,o.y,ssum);
    ssum = fmaf(o.z,o.z,ssum); ssum = fmaf(o.w,o.w,ssum);
    op[c4] = o;
  }
  sqo[n] = ssum;
}

#define CE(va,ia,vb,ib) { bool sw_ = (vb) < (va); float t1_ = sw_?(vb):(va); float t2_ = sw_?(va):(vb); int t3_ = sw_?(ib):(ia); int t4_ = sw_?(ia):(ib); (va)=t1_; (vb)=t2_; (ia)=t3_; (ib)=t4_; }

// ---------------- fused distance GEMM + per-32-group top-3 (K-split depth 16) ----------------
// grid = dim3(24, 24, NB). Block: 128q x 128c tile, 8x8 acc per thread.
// Summaries (tile-major AoS): topv[b][tile][q][12] (4 groups x 3 floats,
// 48B contiguous per row-tile), topi[b][tile][q][4] u32 = i0 | i1<<8.
// Per row: branchless top-3 insert over the thread's 8 cands, then 2-level
// shfl_xor(1,2) sorted-3 merge across the 4 lanes of the 32-cand group.
__global__ __launch_bounds__(256) void disttop_kernel(const float* __restrict__ feat,
    const float* __restrict__ sqn, float* __restrict__ topv, unsigned int* __restrict__ topi){
  __shared__ float As[16][128];
  __shared__ float Bs[16][128];
  int b  = blockIdx.z;
  int m0 = blockIdx.x * 128;
  int q0 = blockIdx.y * 128;
  const float* fb = feat + (size_t)b*NPB*HD;
  int t = threadIdx.x;
  int tx = t & 15, ty = t >> 4;
  float acc[8][8];
  #pragma unroll
  for (int i = 0; i < 8; i++)
    #pragma unroll
    for (int j = 0; j < 8; j++) acc[i][j] = 0.f;
  #pragma unroll 1
  for (int stage = 0; stage < 4; stage++){
    if (stage) __syncthreads();
    {
      int r = t >> 1, dc = (t & 1) * 8;
      const float4* pa = (const float4*)(fb + (size_t)(q0 + r)*HD + stage*16 + dc);
      const float4* pb = (const float4*)(fb + (size_t)(m0 + r)*HD + stage*16 + dc);
      #pragma unroll
      for (int i = 0; i < 2; i++){
        float4 va = pa[i], vb = pb[i];
        int d = dc + i*4;
        As[d][r]=va.x; As[d+1][r]=va.y; As[d+2][r]=va.z; As[d+3][r]=va.w;
        Bs[d][r]=vb.x; Bs[d+1][r]=vb.y; Bs[d+2][r]=vb.z; Bs[d+3][r]=vb.w;
      }
    }
    __syncthreads();
    #pragma unroll 2
    for (int d = 0; d < 16; d++){
      float af[8], bf[8];
      *(float4*)&af[0] = *(const float4*)&As[d][ty*8];
      *(float4*)&af[4] = *(const float4*)&As[d][ty*8+4];
      *(float4*)&bf[0] = *(const float4*)&Bs[d][tx*8];
      *(float4*)&bf[4] = *(const float4*)&Bs[d][tx*8+4];
      #pragma unroll
      for (int i = 0; i < 8; i++)
        #pragma unroll
        for (int j = 0; j < 8; j++)
          acc[i][j] = fmaf(af[i], bf[j], acc[i][j]);
    }
  }
  float sqv[8];
  {
    const float4* sp = (const float4*)(sqn + (size_t)b*NPB + m0 + tx*8);
    float4 sq0 = sp[0], sq1 = sp[1];
    sqv[0]=sq0.x; sqv[1]=sq0.y; sqv[2]=sq0.z; sqv[3]=sq0.w;
    sqv[4]=sq1.x; sqv[5]=sq1.y; sqv[6]=sq1.z; sqv[7]=sq1.w;
  }
  const float INF = 3.4e38f;
  #pragma unroll
  for (int i = 0; i < 8; i++){
    int qg = q0 + ty*8 + i;        // in-batch query index
    int cex = qg - m0;             // diagonal local cand (may be out of range)
    float s0=INF, s1=INF, s2=INF;
    int i0=0, i1=0, i2=0;
    #pragma unroll
    for (int j = 0; j < 8; j++){
      int c = tx*8 + j;
      float v = fmaf(-2.f, acc[i][j], sqv[j]);
      if (c == cex) v = INF;
      bool l2 = v < s2, l1 = v < s1, l0 = v < s0;
      s2 = l1 ? s1 : (l2 ? v : s2);  i2 = l1 ? i1 : (l2 ? c : i2);
      s1 = l0 ? s0 : (l1 ? v : s1);  i1 = l0 ? i0 : (l1 ? c : i1);
      s0 = l0 ? v : s0;              i0 = l0 ? c : i0;
    }
    // 2-level merge of sorted-3 lists across the 4 lanes of the 32-cand group
    #pragma unroll
    for (int off = 1; off < 4; off <<= 1){
      float b0 = __shfl_xor(s0,off,64), b1 = __shfl_xor(s1,off,64), b2 = __shfl_xor(s2,off,64);
      int  bj0 = __shfl_xor(i0,off,64), bj1 = __shfl_xor(i1,off,64), bj2 = __shfl_xor(i2,off,64);
      bool c0 = s0 <= b2; float w0 = c0 ? s0 : b2; int x0 = c0 ? i0 : bj2;
      bool c1 = s1 <= b1; float w1 = c1 ? s1 : b1; int x1 = c1 ? i1 : bj1;
      bool c2 = s2 <= b0; float w2 = c2 ? s2 : b0; int x2 = c2 ? i2 : bj0;
      CE(w0,x0,w1,x1); CE(w0,x0,w2,x2); CE(w1,x1,w2,x2);
      s0=w0; s1=w1; s2=w2; i0=x0; i1=x1; i2=x2;
    }
    if ((tx & 3) == 0){
      size_t rb = ((size_t)(b*NTILE + blockIdx.x)*NPB + qg);
      float* vq = topv + rb*12 + (tx >> 2)*3;
      vq[0] = s0; vq[1] = s1; vq[2] = s2;
      topi[rb*4 + (tx >> 2)] = (unsigned)i0 | ((unsigned)i1 << 8);
    }
  }
}

// ---------------- exact top-20 from per-group top-3 summaries ----------------
// One wave per query. T = 20th smallest of the 64 collapsed group minima
// (actual row values => T >= v20). Group clean iff stored 3rd > T: then all
// its <=T values are the stored 1st/2nd (collected). Flagged groups (3rd<=T)
// are recomputed over their 32 cands with the bitwise-identical fma chain.
// Lex bitonic on (monotone_f32<<32|idx) -> exact top-20 (top_k tie-break).
__global__ __launch_bounds__(256) void ksel_kernel(const float* __restrict__ topv,
    const unsigned int* __restrict__ topi, const float* __restrict__ feat,
    const float* __restrict__ sqn, int* __restrict__ idxout){
  __shared__ float cvs[4][72];
  __shared__ int   cxs[4][72];
  int wid = threadIdx.x >> 6, lane = threadIdx.x & 63;
  int g = blockIdx.x*4 + wid;
  int b = g / NPB;
  int ql = g - b*NPB;
  const float INF = 3.4e38f;
  // slot a: group gg = lane (tile = lane>>2, grp = lane&3)
  float ma, sa, ta; int ja, ka;
  {
    size_t rb = ((size_t)(b*NTILE + (lane >> 2))*NPB + ql);
    const float* va = topv + rb*12 + (lane & 3)*3;
    ma = va[0]; sa = va[1]; ta = va[2];
    unsigned pk = topi[rb*4 + (lane & 3)];
    ja = (int)(pk & 255u); ka = (int)((pk >> 8) & 255u);
  }
  // slot b: group gg = 64+lane (lane < 32)
  float mb = INF, sb = INF, tb = INF;
  int jb = 0, kb = 0;
  if (lane < 32){
    int gg = 64 + lane;
    size_t rb = ((size_t)(b*NTILE + (gg >> 2))*NPB + ql);
    const float* vb_ = topv + rb*12 + (gg & 3)*3;
    mb = vb_[0]; sb = vb_[1]; tb = vb_[2];
    unsigned pk = topi[rb*4 + (gg & 3)];
    jb = (int)(pk & 255u); kb = (int)((pk >> 8) & 255u);
  }
  // threshold: 20th smallest of 64 collapsed group minima
  float T;
  {
    float v = fminf(ma, mb);
    #pragma unroll
    for (int k = 2; k <= 64; k <<= 1){
      #pragma unroll
      for (int j = k >> 1; j > 0; j >>= 1){
        float o = __shfl_xor(v, j, 64);
        bool up    = ((lane & k) == 0);
        bool lower = ((lane & j) == 0);
        float mn = fminf(v, o), mx = fmaxf(v, o);
        v = (lower == up) ? mn : mx;
      }
    }
    T = __shfl(v, 19, 64);
  }
  bool cleanA = (ta > T);
  bool cleanB = (tb > T);          // lanes>=32 have tb=INF -> clean, never fire
  // collect stored qualifiers from clean groups
  float* cv = cvs[wid]; int* cx = cxs[wid];
  int base = 0;
  {
    bool f = cleanA && (ma <= T);
    unsigned long long mk = __ballot(f);
    int pos = (int)__popcll(mk & ((1ull<<lane)-1ull));
    if (f && pos < 64){ cv[pos] = ma; cx[pos] = (lane>>2)*128 + ja; }
    base = (int)__popcll(mk);
    f = cleanA && (sa <= T);
    mk = __ballot(f);
    pos = base + (int)__popcll(mk & ((1ull<<lane)-1ull));
    if (f && pos < 64){ cv[pos] = sa; cx[pos] = (lane>>2)*128 + ka; }
    base += (int)__popcll(mk);
    f = (lane < 32) && cleanB && (mb <= T);
    mk = __ballot(f);
    pos = base + (int)__popcll(mk & ((1ull<<lane)-1ull));
    if (f && pos < 64){ cv[pos] = mb; cx[pos] = ((64+lane)>>2)*128 + jb; }
    base += (int)__popcll(mk);
    f = (lane < 32) && cleanB && (sb <= T);
    mk = __ballot(f);
    pos = base + (int)__popcll(mk & ((1ull<<lane)-1ull));
    if (f && pos < 64){ cv[pos] = sb; cx[pos] = ((64+lane)>>2)*128 + kb; }
    base += (int)__popcll(mk);
  }
  // flagged groups: 3rd <= T -> rescan all 32 cands
  unsigned long long fa = __ballot(!cleanA);
  unsigned long long fbm = __ballot((lane < 32) && !cleanB);
  const float* fqp = feat + (size_t)g*HD;
  #pragma unroll 1
  for (int w = 0; w < 2; w++){
    unsigned long long fm = (w==0) ? fa : fbm;
    int gofs = (w==0) ? 0 : 64;
    while (fm){
      int p = __ffsll((unsigned long long)fm) - 1; fm &= fm - 1;
      int gg = gofs + p;                   // global group id 0..95
      int mbase = (gg >> 2)*128 + (gg & 3)*32;
      bool fire = false; float s = 0.f;
      if (lane < 32){
        int m = mbase + lane;
        const float* fmp = feat + (size_t)(b*NPB + m)*HD;
        float acc = 0.f;
        #pragma unroll
        for (int d4 = 0; d4 < 16; d4++){
          float4 fq4 = *(const float4*)(fqp + d4*4);
          float4 fm4 = *(const float4*)(fmp + d4*4);
          acc = fmaf(fq4.x, fm4.x, acc);
          acc = fmaf(fq4.y, fm4.y, acc);
          acc = fmaf(fq4.z, fm4.z, acc);
          acc = fmaf(fq4.w, fm4.w, acc);
        }
        s = fmaf(-2.f, acc, sqn[(size_t)b*NPB + m]);
        fire = (m != ql) && (s <= T);
      }
      unsigned long long mk2 = __ballot(fire);
      int p2 = base + (int)__popcll(mk2 & ((1ull<<lane)-1ull));
      if (fire && p2 < 64){ cv[p2] = s; cx[p2] = mbase + lane; }
      base += (int)__popcll(mk2);
    }
  }
  if (base <= 64){
    unsigned long long key;
    if (lane < base){
      unsigned int ku = __float_as_uint(cv[lane]);
      ku ^= (unsigned)(((int)ku) >> 31) | 0x80000000u;
      key = ((unsigned long long)ku << 32) | (unsigned int)cx[lane];
    } else key = ~0ull;
    #pragma unroll
    for (int k = 2; k <= 64; k <<= 1){
      #pragma unroll
      for (int j = k >> 1; j > 0; j >>= 1){
        unsigned long long o = __shfl_xor(key, j, 64);
        bool up    = ((lane & k) == 0);
        bool lower = ((lane & j) == 0);
        unsigned long long mn = key < o ? key : o;
        unsigned long long mx = key < o ? o : key;
        key = (lower == up) ? mn : mx;
      }
    }
    if (lane < KNN)
      idxout[(size_t)g*KNN + lane] = b*NPB + (int)(unsigned int)(key & 0xffffffffu);
  } else {
    // degenerate-tie fallback: full recompute, per-lane insert + 20-round merge
    float dl[KNN]; int il[KNN];
    #pragma unroll
    for (int k = 0; k < KNN; k++){ dl[k] = INF; il[k] = 0x7fffffff; }
    #pragma unroll 1
    for (int j = 0; j < 48; j++){
      int m = j*64 + lane;
      if (m == ql) continue;
      const float* fmp = feat + (size_t)(b*NPB + m)*HD;
      float acc = 0.f;
      for (int d4 = 0; d4 < 16; d4++){
        float4 fq4 = *(const float4*)(fqp + d4*4);
        float4 fm4 = *(const float4*)(fmp + d4*4);
        acc = fmaf(fq4.x, fm4.x, acc);
        acc = fmaf(fq4.y, fm4.y, acc);
        acc = fmaf(fq4.z, fm4.z, acc);
        acc = fmaf(fq4.w, fm4.w, acc);
      }
      float s = fmaf(-2.f, acc, sqn[(size_t)b*NPB + m]);
      if (s < dl[KNN-1]){
        #pragma unroll
        for (int k = KNN-1; k >= 1; k--){
          bool c1 = s < dl[k-1];
          bool c0 = s < dl[k];
          dl[k] = c1 ? dl[k-1] : (c0 ? s : dl[k]);
          il[k] = c1 ? il[k-1] : (c0 ? m : il[k]);
        }
        if (s < dl[0]){ dl[0] = s; il[0] = m; }
      }
    }
    int res = 0;
    #pragma unroll 1
    for (int r = 0; r < KNN; r++){
      float d = dl[0]; int i = il[0];
      #pragma unroll
      for (int off = 1; off < 64; off <<= 1){
        float od = __shfl_xor(d, off, 64);
        int   oi = __shfl_xor(i, off, 64);
        if (od < d || (od == d && oi < i)){ d = od; i = oi; }
      }
      if (lane == r) res = i;
      if (il[0] == i){
        #pragma unroll
        for (int k = 0; k < KNN-1; k++){ dl[k] = dl[k+1]; il[k] = il[k+1]; }
        dl[KNN-1] = INF; il[KNN-1] = 0x7fffffff;
      }
    }
    if (lane < KNN) idxout[(size_t)g*KNN + lane] = b*NPB + res;
  }
}

// ---------------- edge-conv factorization: u = x@(Wt-Wb)+b, v = x@Wb ----------------
__global__ __launch_bounds__(256) void uv_kernel(const float* __restrict__ feat,
    const float* __restrict__ W, const float* __restrict__ cb,
    float* __restrict__ u, float* __restrict__ v){
  __shared__ float sW[128*64];
  int t = threadIdx.x;
  for (int i = t; i < 8192; i += 256) sW[i] = W[i];
  __syncthreads();
  int n = blockIdx.x*256 + t;
  float4 fv[16];
  const float4* fp = (const float4*)(feat + (size_t)n*64);
  #pragma unroll
  for (int i = 0; i < 16; i++) fv[i] = fp[i];
  float4* up = (float4*)(u + (size_t)n*64);
  float4* vp = (float4*)(v + (size_t)n*64);
  #pragma unroll 1
  for (int c4 = 0; c4 < 16; c4++){
    float ua0=0,ua1=0,ua2=0,ua3=0, vb0=0,vb1=0,vb2=0,vb3=0;
    #pragma unroll
    for (int d4 = 0; d4 < 16; d4++){
      float4 fq = fv[d4];
      #pragma unroll
      for (int dd = 0; dd < 4; dd++){
        int d = d4*4 + dd;
        float fd = dd==0?fq.x : dd==1?fq.y : dd==2?fq.z : fq.w;
        float4 wt = *(const float4*)&sW[d*64 + c4*4];
        float4 wb = *(const float4*)&sW[(64+d)*64 + c4*4];
        ua0=fmaf(fd,wt.x,ua0); ua1=fmaf(fd,wt.y,ua1); ua2=fmaf(fd,wt.z,ua2); ua3=fmaf(fd,wt.w,ua3);
        vb0=fmaf(fd,wb.x,vb0); vb1=fmaf(fd,wb.y,vb1); vb2=fmaf(fd,wb.z,vb2); vb3=fmaf(fd,wb.w,vb3);
      }
    }
    float4 cbv = *(const float4*)&cb[c4*4];
    float4 uo, vo;
    uo.x = cbv.x + ua0 - vb0; uo.y = cbv.y + ua1 - vb1;
    uo.z = cbv.z + ua2 - vb2; uo.w = cbv.w + ua3 - vb3;
    vo.x = vb0; vo.y = vb1; vo.z = vb2; vo.w = vb3;
    up[c4] = uo; vp[c4] = vo;
  }
}

// ---------------- max-pool + BN + residual + sq of output (one wave per node) ----------------
__global__ __launch_bounds__(256) void pool_kernel(const float* __restrict__ u, const float* __restrict__ v,
    const int* __restrict__ idx, const float* __restrict__ resid,
    const float* __restrict__ bg, const float* __restrict__ bb,
    const float* __restrict__ bm, const float* __restrict__ bv,
    float* __restrict__ out, float* __restrict__ sqo){
  int gid = blockIdx.x*256 + threadIdx.x;
  int n = gid >> 6, lane = gid & 63;
  float uc = u[(size_t)n*64 + lane];
  float scale = bg[lane] / sqrtf(bv[lane] + 1e-5f);
  float bias  = bb[lane] - bm[lane]*scale;
  const int* ip = idx + (size_t)n*KNN;
  float acc = -3.4e38f;
  #pragma unroll 4
  for (int k = 0; k < KNN; k++){
    int j = ip[k];
    float s = uc + v[(size_t)j*64 + lane];
    acc = fmaxf(acc, fmaf(elu_f(s), scale, bias));
  }
  float val = acc + resid[(size_t)n*64 + lane];
  out[(size_t)n*64 + lane] = val;
  float ss = val*val;
  #pragma unroll
  for (int off = 1; off < 64; off <<= 1) ss += __shfl_xor(ss, off, 64);
  if (lane == 0) sqo[n] = ss;
}

// ---------------- CSR build over dst (edges + self loops) ----------------
__global__ void deg_init(int* deg){ int i = blockIdx.x*256 + threadIdx.x; if (i < NTOT) deg[i] = 1; }
__global__ void deg_hist(const int* __restrict__ ei, int E, int* deg){
  int i = blockIdx.x*256 + threadIdx.x; if (i < E) atomicAdd(&deg[ei[E + i]], 1);
}
__global__ void scan_kernel(const int* __restrict__ deg, int* __restrict__ rowptr, int* __restrict__ cursor){
  __shared__ int part[256];
  int t = threadIdx.x;
  int base = t*96;
  int s = 0;
  for (int i = 0; i < 96; i++) s += deg[base + i];
  part[t] = s;
  __syncthreads();
  for (int off = 1; off < 256; off <<= 1){
    int xv = (t >= off) ? part[t - off] : 0;
    __syncthreads();
    part[t] += xv;
    __syncthreads();
  }
  int run = part[t] - s;
  for (int i = 0; i < 96; i++){
    rowptr[base + i] = run; cursor[base + i] = run; run += deg[base + i];
  }
  if (t == 255) rowptr[NTOT] = run;
}
__global__ void scatter_kernel(const int* __restrict__ ei, int E, int* cursor, int* __restrict__ csr){
  int i = blockIdx.x*256 + threadIdx.x;
  if (i >= E + NTOT) return;
  int s, d;
  if (i < E){ s = ei[i]; d = ei[E + i]; } else { s = i - E; d = s; }
  int pos = atomicAdd(&cursor[d], 1);
  csr[pos] = s;
}

// ---------------- GAT: xh = x@W (NT,256), al_s/al_d per head ----------------
__global__ __launch_bounds__(256) void xh_kernel(const float* __restrict__ feat,
    const float* __restrict__ W, const float* __restrict__ asrc, const float* __restrict__ adst,
    float* __restrict__ xh, float* __restrict__ al){
  __shared__ float sW[64*128];
  __shared__ float sas[256], sad[256];
  int t = threadIdx.x;
  if (t < 256){ sas[t] = asrc[t]; sad[t] = adst[t]; }
  int n = blockIdx.x*256 + t;
  float4 fv[16];
  const float4* fp = (const float4*)(feat + (size_t)n*64);
  #pragma unroll
  for (int i = 0; i < 16; i++) fv[i] = fp[i];
  float4* xp = (float4*)(xh + (size_t)n*256);
  float* ap = al + (size_t)n*8;
  #pragma unroll 1
  for (int half = 0; half < 2; half++){
    __syncthreads();
    for (int i = t; i < 8192; i += 256){
      int d = i >> 7, c = i & 127;
      sW[i] = W[d*256 + half*128 + c];
    }
    __syncthreads();
    #pragma unroll 1
    for (int hh = 0; hh < 2; hh++){
      int h = half*2 + hh;
      float as_ = 0.f, ad_ = 0.f;
      #pragma unroll 1
      for (int cc = 0; cc < 64; cc += 4){
        int c  = h*64 + cc;
        int cl = hh*64 + cc;
        float a0=0,a1=0,a2=0,a3=0;
        #pragma unroll
        for (int d4 = 0; d4 < 16; d4++){
          float4 fq = fv[d4];
          #pragma unroll
          for (int dd = 0; dd < 4; dd++){
            int d = d4*4 + dd;
            float fd = dd==0?fq.x : dd==1?fq.y : dd==2?fq.z : fq.w;
            float4 wv = *(const float4*)&sW[d*128 + cl];
            a0=fmaf(fd,wv.x,a0); a1=fmaf(fd,wv.y,a1); a2=fmaf(fd,wv.z,a2); a3=fmaf(fd,wv.w,a3);
          }
        }
        float4 o; o.x=a0; o.y=a1; o.z=a2; o.w=a3;
        xp[c >> 2] = o;
        as_ = fmaf(a0, sas[c], fmaf(a1, sas[c+1], fmaf(a2, sas[c+2], fmaf(a3, sas[c+3], as_))));
        ad_ = fmaf(a0, sad[c], fmaf(a1, sad[c+1], fmaf(a2, sad[c+2], fmaf(a3, sad[c+3], ad_))));
      }
      ap[h] = as_; ap[4 + h] = ad_;
    }
  }
}

// ---------------- GAT aggregation: one-pass online softmax, one wave per dst ----------------
__global__ __launch_bounds__(256) void agg_kernel(const float* __restrict__ xh, const float* __restrict__ al,
    const int* __restrict__ rowptr, const int* __restrict__ csr,
    const float* __restrict__ resid, const float* __restrict__ bias,
    float* __restrict__ out){
  int gid = blockIdx.x*256 + threadIdx.x;
  int n = gid >> 6, lane = gid & 63;
  int rs = rowptr[n], re = rowptr[n+1];
  int h = lane >> 4, coff = (lane & 15)*4;
  float ald_h = al[(size_t)n*8 + 4 + h];
  float mx = -3.4e38f, den = 0.f;
  float ax=0.f, ay=0.f, az=0.f, aw=0.f;
  #pragma unroll 2
  for (int e = rs; e < re; e++){
    int s = csr[e];
    float a = al[(size_t)s*8 + h] + ald_h;
    a = a > 0.f ? a : 0.2f*a;                   // leaky_relu
    float nm = fmaxf(mx, a);
    float corr = __expf(mx - nm);
    float ea   = __expf(a - nm);
    mx = nm;
    float4 xv = *(const float4*)(xh + (size_t)s*256 + h*64 + coff);
    den = fmaf(den, corr, ea);
    ax = fmaf(ax, corr, ea*xv.x); ay = fmaf(ay, corr, ea*xv.y);
    az = fmaf(az, corr, ea*xv.z); aw = fmaf(aw, corr, ea*xv.w);
  }
  float rinv = 1.f / (den + 1e-16f);
  float r0 = ax*rinv, r1 = ay*rinv, r2 = az*rinv, r3 = aw*rinv;
  r0 += __shfl_xor(r0, 16, 64); r1 += __shfl_xor(r1, 16, 64);
  r2 += __shfl_xor(r2, 16, 64); r3 += __shfl_xor(r3, 16, 64);
  r0 += __shfl_xor(r0, 32, 64); r1 += __shfl_xor(r1, 32, 64);
  r2 += __shfl_xor(r2, 32, 64); r3 += __shfl_xor(r3, 32, 64);
  if (lane < 16){
    float4 bs = *(const float4*)(bias + coff);
    float4 rv = *(const float4*)(resid + (size_t)n*64 + coff);
    float4 o;
    o.x = r0*0.25f + bs.x + rv.x; o.y = r1*0.25f + bs.y + rv.y;
    o.z = r2*0.25f + bs.z + rv.z; o.w = r3*0.25f + bs.w + rv.w;
    *(float4*)(out + (size_t)n*64 + coff) = o;
  }
}

// ---------------- output MLP: 64->64 elu ->32 elu ->8 ----------------
__global__ __launch_bounds__(256) void mlp_kernel(const float* __restrict__ feat,
    const float* __restrict__ W1, const float* __restrict__ b1,
    const float* __restrict__ W2, const float* __restrict__ b2,
    const float* __restrict__ W3, const float* __restrict__ b3,
    float* __restrict__ out){
  __shared__ float s1[4096], s2[2048], s3[256], t1[64], t2[32], t3[8];
  int t = threadIdx.x;
  for (int i = t; i < 4096; i += 256) s1[i] = W1[i];
  for (int i = t; i < 2048; i += 256) s2[i] = W2[i];
  if (t < 256) s3[t] = W3[t];
  if (t < 64) t1[t] = b1[t];
  if (t < 32) t2[t] = b2[t];
  if (t < 8)  t3[t] = b3[t];
  __syncthreads();
  int n = blockIdx.x*256 + t;
  float4 fv[16];
  const float4* fp = (const float4*)(feat + (size_t)n*64);
  #pragma unroll
  for (int i = 0; i < 16; i++) fv[i] = fp[i];
  float o1[64];
  #pragma unroll 1
  for (int c4 = 0; c4 < 16; c4++){
    float a0=t1[c4*4+0], a1=t1[c4*4+1], a2=t1[c4*4+2], a3=t1[c4*4+3];
    #pragma unroll
    for (int d4 = 0; d4 < 16; d4++){
      float4 fq = fv[d4];
      #pragma unroll
      for (int dd = 0; dd < 4; dd++){
        int d = d4*4 + dd;
        float fd = dd==0?fq.x : dd==1?fq.y : dd==2?fq.z : fq.w;
        float4 wv = *(const float4*)&s1[d*64 + c4*4];
        a0=fmaf(fd,wv.x,a0); a1=fmaf(fd,wv.y,a1); a2=fmaf(fd,wv.z,a2); a3=fmaf(fd,wv.w,a3);
      }
    }
    o1[c4*4+0]=elu_f(a0); o1[c4*4+1]=elu_f(a1); o1[c4*4+2]=elu_f(a2); o1[c4*4+3]=elu_f(a3);
  }
  float o2[32];
  #pragma unroll 1
  for (int c4 = 0; c4 < 8; c4++){
    float a0=t2[c4*4+0], a1=t2[c4*4+1], a2=t2[c4*4+2], a3=t2[c4*4+3];
    #pragma unroll
    for (int d = 0; d < 64; d++){
      float fd = o1[d];
      float4 wv = *(const float4*)&s2[d*32 + c4*4];
      a0=fmaf(fd,wv.x,a0); a1=fmaf(fd,wv.y,a1); a2=fmaf(fd,wv.z,a2); a3=fmaf(fd,wv.w,a3);
    }
    o2[c4*4+0]=elu_f(a0); o2[c4*4+1]=elu_f(a1); o2[c4*4+2]=elu_f(a2); o2[c4*4+3]=elu_f(a3);
  }
  float4* op = (float4*)(out + (size_t)n*8);
  #pragma unroll
  for (int c4 = 0; c4 < 2; c4++){
    float a0=t3[c4*4+0], a1=t3[c4*4+1], a2=t3[c4*4+2], a3=t3[c4*4+3];
    #pragma unroll
    for (int d = 0; d < 32; d++){
      float fd = o2[d];
      float4 wv = *(const float4*)&s3[d*8 + c4*4];
      a0=fmaf(fd,wv.x,a0); a1=fmaf(fd,wv.y,a1); a2=fmaf(fd,wv.z,a2); a3=fmaf(fd,wv.w,a3);
    }
    float4 o; o.x=a0; o.y=a1; o.z=a2; o.w=a3;
    op[c4] = o;
  }
}

extern "C" void kernel_launch(void* const* d_in, const int* in_sizes, int n_in,
                              void* d_out, int out_size, void* d_ws, size_t ws_size,
                              hipStream_t stream){
  (void)n_in; (void)out_size; (void)ws_size;
  const float* x     = (const float*)d_in[0];
  const int*   ei    = (const int*)d_in[2];
  const int    E     = in_sizes[2] / 2;
  const float* encW1 = (const float*)d_in[3];
  const float* encb1 = (const float*)d_in[4];
  const float* encW2 = (const float*)d_in[5];
  const float* encb2 = (const float*)d_in[6];
  const float* convW = (const float*)d_in[7];
  const float* convb = (const float*)d_in[8];
  const float* bng   = (const float*)d_in[9];
  const float* bnb   = (const float*)d_in[10];
  const float* bnm   = (const float*)d_in[11];
  const float* bnv   = (const float*)d_in[12];
  const float* gatW  = (const float*)d_in[13];
  const float* gatas = (const float*)d_in[14];
  const float* gatad = (const float*)d_in[15];
  const float* gatb  = (const float*)d_in[16];
  const float* oW1   = (const float*)d_in[17];
  const float* ob1   = (const float*)d_in[18];
  const float* oW2   = (const float*)d_in[19];
  const float* ob2   = (const float*)d_in[20];
  const float* oW3   = (const float*)d_in[21];
  const float* ob3   = (const float*)d_in[22];

  char* wp = (char*)d_ws;
  auto alloc = [&](size_t bytes)->void*{
    void* p = (void*)wp; wp += (bytes + 255) & ~((size_t)255); return p;
  };
  float* fA     = (float*)alloc((size_t)NTOT*64*4);
  float* fB     = (float*)alloc((size_t)NTOT*64*4);
  float* ubuf   = (float*)alloc((size_t)NTOT*64*4);
  float* vbuf   = (float*)alloc((size_t)NTOT*64*4);
  float* sqb    = (float*)alloc((size_t)NTOT*4);
  int*   idxb   = (int*)  alloc((size_t)NTOT*KNN*4);
  float* xhb    = (float*)alloc((size_t)NTOT*256*4);
  float* alb    = (float*)alloc((size_t)NTOT*8*4);
  int*   degb   = (int*)  alloc((size_t)NTOT*4);
  int*   rowptr = (int*)  alloc((size_t)(NTOT+1)*4);
  int*   cursor = (int*)  alloc((size_t)NTOT*4);
  int*   csr    = (int*)  alloc((size_t)(E+NTOT)*4);
  float* topv   = (float*)alloc((size_t)NTOT*288*4);
  unsigned int* topi = (unsigned int*)alloc((size_t)NTOT*96*4);

  enc_kernel<<<96,256,0,stream>>>(x, encW1, encb1, encW2, encb2, fA, sqb);
  float* cur = fA; float* nxt = fB;
  for (int l = 0; l < 3; l++){
    disttop_kernel<<<dim3(NTILE,NTILE,NB),256,0,stream>>>(cur, sqb, topv, topi);
    ksel_kernel   <<<NTOT/4,              256,0,stream>>>(topv, topi, cur, sqb, idxb);
    uv_kernel  <<<96,  256,0,stream>>>(cur, convW + (size_t)l*8192, convb + l*64, ubuf, vbuf);
    pool_kernel<<<6144,256,0,stream>>>(ubuf, vbuf, idxb, cur,
                                       bng + l*64, bnb + l*64, bnm + l*64, bnv + l*64, nxt, sqb);
    float* tmp = cur; cur = nxt; nxt = tmp;
  }
  deg_init   <<<96,            256,0,stream>>>(degb);
  deg_hist   <<<(E+255)/256,   256,0,stream>>>(ei, E, degb);
  scan_kernel<<<1,             256,0,stream>>>(degb, rowptr, cursor);
  scatter_kernel<<<(E+NTOT+255)/256,256,0,stream>>>(ei, E, cursor, csr);
  for (int l = 0; l < 2; l++){
    xh_kernel <<<96,  256,0,stream>>>(cur, gatW + (size_t)l*16384, gatas + l*256, gatad + l*256, xhb, alb);
    agg_kernel<<<6144,256,0,stream>>>(xhb, alb, rowptr, csr, cur, gatb + l*64, nxt);
    float* tmp = cur; cur = nxt; nxt = tmp;
  }
  mlp_kernel<<<96,256,0,stream>>>(cur, oW1, ob1, oW2, ob2, oW3, ob3, (float*)d_out);
}

// Round 15
// 1007.564 us; speedup vs baseline: 1.2905x; 1.1179x over previous
//
#include <hip/hip_runtime.h>
#include <math.h>

// Problem constants (match reference)
#define NTOT  24576      // B*N nodes
#define NB    8
#define NPB   3072       // nodes per batch
#define HD    64
#define KNN   20
#define NTILE 24         // NPB/128
#define TPAIRS 300       // NTILE*(NTILE+1)/2 upper-triangle tile pairs

__device__ __forceinline__ float elu_f(float x){ return x > 0.f ? x : expm1f(x); }

// ---------------- encoder: x(NT,8) -> elu(elu(x@W1+b1)@W2+b2) (NT,64) + sq ----------------
__global__ __launch_bounds__(256) void enc_kernel(const float* __restrict__ x,
    const float* __restrict__ W1, const float* __restrict__ b1,
    const float* __restrict__ W2, const float* __restrict__ b2,
    float* __restrict__ out, float* __restrict__ sqo){
  __shared__ float sW1[256], sb1[32], sW2[2048], sb2[64];
  int t = threadIdx.x;
  if (t < 256) sW1[t] = W1[t];
  for (int i = t; i < 2048; i += 256) sW2[i] = W2[i];
  if (t < 32) sb1[t] = b1[t];
  if (t < 64) sb2[t] = b2[t];
  __syncthreads();
  int n = blockIdx.x*256 + t;
  const float4* xp = (const float4*)(x + (size_t)n*8);
  float4 x0 = xp[0], x1 = xp[1];
  float xi[8] = {x0.x,x0.y,x0.z,x0.w,x1.x,x1.y,x1.z,x1.w};
  float h1[32];
  #pragma unroll
  for (int j = 0; j < 32; j++){
    float a = sb1[j];
    #pragma unroll
    for (int d = 0; d < 8; d++) a = fmaf(xi[d], sW1[d*32+j], a);
    h1[j] = elu_f(a);
  }
  float4* op = (float4*)(out + (size_t)n*64);
  float ssum = 0.f;
  #pragma unroll
  for (int c4 = 0; c4 < 16; c4++){
    float a0 = sb2[c4*4+0], a1 = sb2[c4*4+1], a2 = sb2[c4*4+2], a3 = sb2[c4*4+3];
    #pragma unroll
    for (int d = 0; d < 32; d++){
      float hd = h1[d];
      float4 wv = *(const float4*)&sW2[d*64 + c4*4];
      a0 = fmaf(hd, wv.x, a0); a1 = fmaf(hd, wv.y, a1);
      a2 = fmaf(hd, wv.z, a2); a3 = fmaf(hd, wv.w, a3);
    }
    float4 o; o.x=elu_f(a0); o.y=elu_f(a1); o.z=elu_f(a2); o.w=elu_f(a3);
    ssum = fmaf(o.x,o.x,ssum); ssum = fmaf(o.y,o.y,ssum);
    ssum = fmaf(o.z,o.z,ssum); ssum = fmaf(o.w,o.w,ssum);
    op[c4] = o;
  }
  sqo[n] = ssum;
}

#define CE(va,ia,vb,ib) { bool sw_ = (vb) < (va); float t1_ = sw_?(vb):(va); float t2_ = sw_?(va):(vb); int t3_ = sw_?(ib):(ia); int t4_ = sw_?(ia):(ib); (va)=t1_; (vb)=t2_; (ia)=t3_; (ib)=t4_; }

// ---------------- fused distance GEMM + per-32-group top-3, SYMMETRIC tiles ----------------
// grid = dim3(TPAIRS, 1, NB): only upper-triangle tile pairs (tq<=tm).
// Off-diagonal tiles extract BOTH directions from the same acc registers:
//  - row-dir: queries = rows (q0 range), cands = cols (m0 range), write tile tm
//  - col-dir: queries = cols (m0 range), cands = rows (q0 range), write tile tq
// IEEE multiply commutes and d-order is identical -> col distances bitwise
// match the mirrored tile's row distances (ksel contract preserved).
// Summaries (tile-major AoS): topv[b][tile][q][12], topi[b][tile][q][4].
__global__ __launch_bounds__(256) void disttop_kernel(const float* __restrict__ feat,
    const float* __restrict__ sqn, float* __restrict__ topv, unsigned int* __restrict__ topi){
  __shared__ float As[16][128];
  __shared__ float Bs[16][128];
  int b = blockIdx.z;
  int L = blockIdx.x, tq = 0;
  while (L >= NTILE - tq){ L -= NTILE - tq; tq++; }   // decode upper-tri pair
  int tm = tq + L;
  int q0 = tq*128, m0 = tm*128;
  const float* fb = feat + (size_t)b*NPB*HD;
  int t = threadIdx.x;
  int tx = t & 15, ty = t >> 4;
  float acc[8][8];
  #pragma unroll
  for (int i = 0; i < 8; i++)
    #pragma unroll
    for (int j = 0; j < 8; j++) acc[i][j] = 0.f;
  #pragma unroll 1
  for (int stage = 0; stage < 4; stage++){
    if (stage) __syncthreads();
    {
      int r = t >> 1, dc = (t & 1) * 8;
      const float4* pa = (const float4*)(fb + (size_t)(q0 + r)*HD + stage*16 + dc);
      const float4* pb = (const float4*)(fb + (size_t)(m0 + r)*HD + stage*16 + dc);
      #pragma unroll
      for (int i = 0; i < 2; i++){
        float4 va = pa[i], vb = pb[i];
        int d = dc + i*4;
        As[d][r]=va.x; As[d+1][r]=va.y; As[d+2][r]=va.z; As[d+3][r]=va.w;
        Bs[d][r]=vb.x; Bs[d+1][r]=vb.y; Bs[d+2][r]=vb.z; Bs[d+3][r]=vb.w;
      }
    }
    __syncthreads();
    #pragma unroll 2
    for (int d = 0; d < 16; d++){
      float af[8], bf[8];
      *(float4*)&af[0] = *(const float4*)&As[d][ty*8];
      *(float4*)&af[4] = *(const float4*)&As[d][ty*8+4];
      *(float4*)&bf[0] = *(const float4*)&Bs[d][tx*8];
      *(float4*)&bf[4] = *(const float4*)&Bs[d][tx*8+4];
      #pragma unroll
      for (int i = 0; i < 8; i++)
        #pragma unroll
        for (int j = 0; j < 8; j++)
          acc[i][j] = fmaf(af[i], bf[j], acc[i][j]);
    }
  }
  float sqv[8];   // sq of col (m0) range
  {
    const float4* sp = (const float4*)(sqn + (size_t)b*NPB + m0 + tx*8);
    float4 sq0 = sp[0], sq1 = sp[1];
    sqv[0]=sq0.x; sqv[1]=sq0.y; sqv[2]=sq0.z; sqv[3]=sq0.w;
    sqv[4]=sq1.x; sqv[5]=sq1.y; sqv[6]=sq1.z; sqv[7]=sq1.w;
  }
  float sqQ[8];   // sq of row (q0) range
  {
    const float4* sp = (const float4*)(sqn + (size_t)b*NPB + q0 + ty*8);
    float4 sq0 = sp[0], sq1 = sp[1];
    sqQ[0]=sq0.x; sqQ[1]=sq0.y; sqQ[2]=sq0.z; sqQ[3]=sq0.w;
    sqQ[4]=sq1.x; sqQ[5]=sq1.y; sqQ[6]=sq1.z; sqQ[7]=sq1.w;
  }
  const float INF = 3.4e38f;
  // ---- row-direction selection: queries = rows, cands = cols ----
  #pragma unroll
  for (int i = 0; i < 8; i++){
    int qg = q0 + ty*8 + i;
    int cex = qg - m0;             // diagonal local cand (diag tiles only)
    float s0=INF, s1=INF, s2=INF;
    int i0=0, i1=0, i2=0;
    #pragma unroll
    for (int j = 0; j < 8; j++){
      int c = tx*8 + j;
      float v = fmaf(-2.f, acc[i][j], sqv[j]);
      if (c == cex) v = INF;
      bool l2 = v < s2, l1 = v < s1, l0 = v < s0;
      s2 = l1 ? s1 : (l2 ? v : s2);  i2 = l1 ? i1 : (l2 ? c : i2);
      s1 = l0 ? s0 : (l1 ? v : s1);  i1 = l0 ? i0 : (l1 ? c : i1);
      s0 = l0 ? v : s0;              i0 = l0 ? c : i0;
    }
    #pragma unroll
    for (int off = 1; off < 4; off <<= 1){
      float b0 = __shfl_xor(s0,off,64), b1 = __shfl_xor(s1,off,64), b2 = __shfl_xor(s2,off,64);
      int  bj0 = __shfl_xor(i0,off,64), bj1 = __shfl_xor(i1,off,64), bj2 = __shfl_xor(i2,off,64);
      bool c0 = s0 <= b2; float w0 = c0 ? s0 : b2; int x0 = c0 ? i0 : bj2;
      bool c1 = s1 <= b1; float w1 = c1 ? s1 : b1; int x1 = c1 ? i1 : bj1;
      bool c2 = s2 <= b0; float w2 = c2 ? s2 : b0; int x2 = c2 ? i2 : bj0;
      CE(w0,x0,w1,x1); CE(w0,x0,w2,x2); CE(w1,x1,w2,x2);
      s0=w0; s1=w1; s2=w2; i0=x0; i1=x1; i2=x2;
    }
    if ((tx & 3) == 0){
      size_t rb = ((size_t)(b*NTILE + tm)*NPB + qg);
      float* vq = topv + rb*12 + (tx >> 2)*3;
      vq[0] = s0; vq[1] = s1; vq[2] = s2;
      topi[rb*4 + (tx >> 2)] = (unsigned)i0 | ((unsigned)i1 << 8);
    }
  }
  // ---- col-direction selection (off-diagonal only): queries = cols, cands = rows ----
  if (tm != tq){
    #pragma unroll
    for (int j = 0; j < 8; j++){
      int qc = m0 + tx*8 + j;
      float s0=INF, s1=INF, s2=INF;
      int i0=0, i1=0, i2=0;
      #pragma unroll
      for (int i = 0; i < 8; i++){
        int c = ty*8 + i;          // tile-local row idx (0..127)
        float v = fmaf(-2.f, acc[i][j], sqQ[i]);
        bool l2 = v < s2, l1 = v < s1, l0 = v < s0;
        s2 = l1 ? s1 : (l2 ? v : s2);  i2 = l1 ? i1 : (l2 ? c : i2);
        s1 = l0 ? s0 : (l1 ? v : s1);  i1 = l0 ? i0 : (l1 ? c : i1);
        s0 = l0 ? v : s0;              i0 = l0 ? c : i0;
      }
      // merge across the 4 lanes sharing tx within the wave (ty&3 = 0..3)
      #pragma unroll
      for (int off = 16; off < 64; off <<= 1){
        float b0 = __shfl_xor(s0,off,64), b1 = __shfl_xor(s1,off,64), b2 = __shfl_xor(s2,off,64);
        int  bj0 = __shfl_xor(i0,off,64), bj1 = __shfl_xor(i1,off,64), bj2 = __shfl_xor(i2,off,64);
        bool c0 = s0 <= b2; float w0 = c0 ? s0 : b2; int x0 = c0 ? i0 : bj2;
        bool c1 = s1 <= b1; float w1 = c1 ? s1 : b1; int x1 = c1 ? i1 : bj1;
        bool c2 = s2 <= b0; float w2 = c2 ? s2 : b0; int x2 = c2 ? i2 : bj0;
        CE(w0,x0,w1,x1); CE(w0,x0,w2,x2); CE(w1,x1,w2,x2);
        s0=w0; s1=w1; s2=w2; i0=x0; i1=x1; i2=x2;
      }
      if ((ty & 3) == 0){
        size_t rb = ((size_t)(b*NTILE + tq)*NPB + qc);
        float* vq = topv + rb*12 + (ty >> 2)*3;
        vq[0] = s0; vq[1] = s1; vq[2] = s2;
        topi[rb*4 + (ty >> 2)] = (unsigned)i0 | ((unsigned)i1 << 8);
      }
    }
  }
}

// ---------------- exact top-20 from per-group top-3 summaries ----------------
// One wave per query. T = 20th smallest of the 64 collapsed group minima
// (actual row values => T >= v20). Group clean iff stored 3rd > T: then all
// its <=T values are the stored 1st/2nd (collected). Flagged groups (3rd<=T)
// are recomputed over their 32 cands with the bitwise-identical fma chain.
// Lex bitonic on (monotone_f32<<32|idx) -> exact top-20 (top_k tie-break).
__global__ __launch_bounds__(256) void ksel_kernel(const float* __restrict__ topv,
    const unsigned int* __restrict__ topi, const float* __restrict__ feat,
    const float* __restrict__ sqn, int* __restrict__ idxout){
  __shared__ float cvs[4][72];
  __shared__ int   cxs[4][72];
  int wid = threadIdx.x >> 6, lane = threadIdx.x & 63;
  int g = blockIdx.x*4 + wid;
  int b = g / NPB;
  int ql = g - b*NPB;
  const float INF = 3.4e38f;
  // slot a: group gg = lane (tile = lane>>2, grp = lane&3)
  float ma, sa, ta; int ja, ka;
  {
    size_t rb = ((size_t)(b*NTILE + (lane >> 2))*NPB + ql);
    const float* va = topv + rb*12 + (lane & 3)*3;
    ma = va[0]; sa = va[1]; ta = va[2];
    unsigned pk = topi[rb*4 + (lane & 3)];
    ja = (int)(pk & 255u); ka = (int)((pk >> 8) & 255u);
  }
  // slot b: group gg = 64+lane (lane < 32)
  float mb = INF, sb = INF, tb = INF;
  int jb = 0, kb = 0;
  if (lane < 32){
    int gg = 64 + lane;
    size_t rb = ((size_t)(b*NTILE + (gg >> 2))*NPB + ql);
    const float* vb_ = topv + rb*12 + (gg & 3)*3;
    mb = vb_[0]; sb = vb_[1]; tb = vb_[2];
    unsigned pk = topi[rb*4 + (gg & 3)];
    jb = (int)(pk & 255u); kb = (int)((pk >> 8) & 255u);
  }
  // threshold: 20th smallest of 64 collapsed group minima
  float T;
  {
    float v = fminf(ma, mb);
    #pragma unroll
    for (int k = 2; k <= 64; k <<= 1){
      #pragma unroll
      for (int j = k >> 1; j > 0; j >>= 1){
        float o = __shfl_xor(v, j, 64);
        bool up    = ((lane & k) == 0);
        bool lower = ((lane & j) == 0);
        float mn = fminf(v, o), mx = fmaxf(v, o);
        v = (lower == up) ? mn : mx;
      }
    }
    T = __shfl(v, 19, 64);
  }
  bool cleanA = (ta > T);
  bool cleanB = (tb > T);          // lanes>=32 have tb=INF -> clean, never fire
  // collect stored qualifiers from clean groups
  float* cv = cvs[wid]; int* cx = cxs[wid];
  int base = 0;
  {
    bool f = cleanA && (ma <= T);
    unsigned long long mk = __ballot(f);
    int pos = (int)__popcll(mk & ((1ull<<lane)-1ull));
    if (f && pos < 64){ cv[pos] = ma; cx[pos] = (lane>>2)*128 + ja; }
    base = (int)__popcll(mk);
    f = cleanA && (sa <= T);
    mk = __ballot(f);
    pos = base + (int)__popcll(mk & ((1ull<<lane)-1ull));
    if (f && pos < 64){ cv[pos] = sa; cx[pos] = (lane>>2)*128 + ka; }
    base += (int)__popcll(mk);
    f = (lane < 32) && cleanB && (mb <= T);
    mk = __ballot(f);
    pos = base + (int)__popcll(mk & ((1ull<<lane)-1ull));
    if (f && pos < 64){ cv[pos] = mb; cx[pos] = ((64+lane)>>2)*128 + jb; }
    base += (int)__popcll(mk);
    f = (lane < 32) && cleanB && (sb <= T);
    mk = __ballot(f);
    pos = base + (int)__popcll(mk & ((1ull<<lane)-1ull));
    if (f && pos < 64){ cv[pos] = sb; cx[pos] = ((64+lane)>>2)*128 + kb; }
    base += (int)__popcll(mk);
  }
  // flagged groups: 3rd <= T -> rescan all 32 cands
  unsigned long long fa = __ballot(!cleanA);
  unsigned long long fbm = __ballot((lane < 32) && !cleanB);
  const float* fqp = feat + (size_t)g*HD;
  #pragma unroll 1
  for (int w = 0; w < 2; w++){
    unsigned long long fm = (w==0) ? fa : fbm;
    int gofs = (w==0) ? 0 : 64;
    while (fm){
      int p = __ffsll((unsigned long long)fm) - 1; fm &= fm - 1;
      int gg = gofs + p;                   // global group id 0..95
      int mbase = (gg >> 2)*128 + (gg & 3)*32;
      bool fire = false; float s = 0.f;
      if (lane < 32){
        int m = mbase + lane;
        const float* fmp = feat + (size_t)(b*NPB + m)*HD;
        float acc = 0.f;
        #pragma unroll
        for (int d4 = 0; d4 < 16; d4++){
          float4 fq4 = *(const float4*)(fqp + d4*4);
          float4 fm4 = *(const float4*)(fmp + d4*4);
          acc = fmaf(fq4.x, fm4.x, acc);
          acc = fmaf(fq4.y, fm4.y, acc);
          acc = fmaf(fq4.z, fm4.z, acc);
          acc = fmaf(fq4.w, fm4.w, acc);
        }
        s = fmaf(-2.f, acc, sqn[(size_t)b*NPB + m]);
        fire = (m != ql) && (s <= T);
      }
      unsigned long long mk2 = __ballot(fire);
      int p2 = base + (int)__popcll(mk2 & ((1ull<<lane)-1ull));
      if (fire && p2 < 64){ cv[p2] = s; cx[p2] = mbase + lane; }
      base += (int)__popcll(mk2);
    }
  }
  if (base <= 64){
    unsigned long long key;
    if (lane < base){
      unsigned int ku = __float_as_uint(cv[lane]);
      ku ^= (unsigned)(((int)ku) >> 31) | 0x80000000u;
      key = ((unsigned long long)ku << 32) | (unsigned int)cx[lane];
    } else key = ~0ull;
    #pragma unroll
    for (int k = 2; k <= 64; k <<= 1){
      #pragma unroll
      for (int j = k >> 1; j > 0; j >>= 1){
        unsigned long long o = __shfl_xor(key, j, 64);
        bool up    = ((lane & k) == 0);
        bool lower = ((lane & j) == 0);
        unsigned long long mn = key < o ? key : o;
        unsigned long long mx = key < o ? o : key;
        key = (lower == up) ? mn : mx;
      }
    }
    if (lane < KNN)
      idxout[(size_t)g*KNN + lane] = b*NPB + (int)(unsigned int)(key & 0xffffffffu);
  } else {
    // degenerate-tie fallback: full recompute, per-lane insert + 20-round merge
    float dl[KNN]; int il[KNN];
    #pragma unroll
    for (int k = 0; k < KNN; k++){ dl[k] = INF; il[k] = 0x7fffffff; }
    #pragma unroll 1
    for (int j = 0; j < 48; j++){
      int m = j*64 + lane;
      if (m == ql) continue;
      const float* fmp = feat + (size_t)(b*NPB + m)*HD;
      float acc = 0.f;
      for (int d4 = 0; d4 < 16; d4++){
        float4 fq4 = *(const float4*)(fqp + d4*4);
        float4 fm4 = *(const float4*)(fmp + d4*4);
        acc = fmaf(fq4.x, fm4.x, acc);
        acc = fmaf(fq4.y, fm4.y, acc);
        acc = fmaf(fq4.z, fm4.z, acc);
        acc = fmaf(fq4.w, fm4.w, acc);
      }
      float s = fmaf(-2.f, acc, sqn[(size_t)b*NPB + m]);
      if (s < dl[KNN-1]){
        #pragma unroll
        for (int k = KNN-1; k >= 1; k--){
          bool c1 = s < dl[k-1];
          bool c0 = s < dl[k];
          dl[k] = c1 ? dl[k-1] : (c0 ? s : dl[k]);
          il[k] = c1 ? il[k-1] : (c0 ? m : il[k]);
        }
        if (s < dl[0]){ dl[0] = s; il[0] = m; }
      }
    }
    int res = 0;
    #pragma unroll 1
    for (int r = 0; r < KNN; r++){
      float d = dl[0]; int i = il[0];
      #pragma unroll
      for (int off = 1; off < 64; off <<= 1){
        float od = __shfl_xor(d, off, 64);
        int   oi = __shfl_xor(i, off, 64);
        if (od < d || (od == d && oi < i)){ d = od; i = oi; }
      }
      if (lane == r) res = i;
      if (il[0] == i){
        #pragma unroll
        for (int k = 0; k < KNN-1; k++){ dl[k] = dl[k+1]; il[k] = il[k+1]; }
        dl[KNN-1] = INF; il[KNN-1] = 0x7fffffff;
      }
    }
    if (lane < KNN) idxout[(size_t)g*KNN + lane] = b*NPB + res;
  }
}

// ---------------- edge-conv factorization: u = x@(Wt-Wb)+b, v = x@Wb ----------------
__global__ __launch_bounds__(256) void uv_kernel(const float* __restrict__ feat,
    const float* __restrict__ W, const float* __restrict__ cb,
    float* __restrict__ u, float* __restrict__ v){
  __shared__ float sW[128*64];
  int t = threadIdx.x;
  for (int i = t; i < 8192; i += 256) sW[i] = W[i];
  __syncthreads();
  int n = blockIdx.x*256 + t;
  float4 fv[16];
  const float4* fp = (const float4*)(feat + (size_t)n*64);
  #pragma unroll
  for (int i = 0; i < 16; i++) fv[i] = fp[i];
  float4* up = (float4*)(u + (size_t)n*64);
  float4* vp = (float4*)(v + (size_t)n*64);
  #pragma unroll 1
  for (int c4 = 0; c4 < 16; c4++){
    float ua0=0,ua1=0,ua2=0,ua3=0, vb0=0,vb1=0,vb2=0,vb3=0;
    #pragma unroll
    for (int d4 = 0; d4 < 16; d4++){
      float4 fq = fv[d4];
      #pragma unroll
      for (int dd = 0; dd < 4; dd++){
        int d = d4*4 + dd;
        float fd = dd==0?fq.x : dd==1?fq.y : dd==2?fq.z : fq.w;
        float4 wt = *(const float4*)&sW[d*64 + c4*4];
        float4 wb = *(const float4*)&sW[(64+d)*64 + c4*4];
        ua0=fmaf(fd,wt.x,ua0); ua1=fmaf(fd,wt.y,ua1); ua2=fmaf(fd,wt.z,ua2); ua3=fmaf(fd,wt.w,ua3);
        vb0=fmaf(fd,wb.x,vb0); vb1=fmaf(fd,wb.y,vb1); vb2=fmaf(fd,wb.z,vb2); vb3=fmaf(fd,wb.w,vb3);
      }
    }
    float4 cbv = *(const float4*)&cb[c4*4];
    float4 uo, vo;
    uo.x = cbv.x + ua0 - vb0; uo.y = cbv.y + ua1 - vb1;
    uo.z = cbv.z + ua2 - vb2; uo.w = cbv.w + ua3 - vb3;
    vo.x = vb0; vo.y = vb1; vo.z = vb2; vo.w = vb3;
    up[c4] = uo; vp[c4] = vo;
  }
}

// ---------------- max-pool + BN + residual + sq of output (one wave per node) ----------------
__global__ __launch_bounds__(256) void pool_kernel(const float* __restrict__ u, const float* __restrict__ v,
    const int* __restrict__ idx, const float* __restrict__ resid,
    const float* __restrict__ bg, const float* __restrict__ bb,
    const float* __restrict__ bm, const float* __restrict__ bv,
    float* __restrict__ out, float* __restrict__ sqo){
  int gid = blockIdx.x*256 + threadIdx.x;
  int n = gid >> 6, lane = gid & 63;
  float uc = u[(size_t)n*64 + lane];
  float scale = bg[lane] / sqrtf(bv[lane] + 1e-5f);
  float bias  = bb[lane] - bm[lane]*scale;
  const int* ip = idx + (size_t)n*KNN;
  float acc = -3.4e38f;
  #pragma unroll 4
  for (int k = 0; k < KNN; k++){
    int j = ip[k];
    float s = uc + v[(size_t)j*64 + lane];
    acc = fmaxf(acc, fmaf(elu_f(s), scale, bias));
  }
  float val = acc + resid[(size_t)n*64 + lane];
  out[(size_t)n*64 + lane] = val;
  float ss = val*val;
  #pragma unroll
  for (int off = 1; off < 64; off <<= 1) ss += __shfl_xor(ss, off, 64);
  if (lane == 0) sqo[n] = ss;
}

// ---------------- CSR build over dst (edges + self loops) ----------------
__global__ void deg_init(int* deg){ int i = blockIdx.x*256 + threadIdx.x; if (i < NTOT) deg[i] = 1; }
__global__ void deg_hist(const int* __restrict__ ei, int E, int* deg){
  int i = blockIdx.x*256 + threadIdx.x; if (i < E) atomicAdd(&deg[ei[E + i]], 1);
}
__global__ void scan_kernel(const int* __restrict__ deg, int* __restrict__ rowptr, int* __restrict__ cursor){
  __shared__ int part[256];
  int t = threadIdx.x;
  int base = t*96;
  int s = 0;
  for (int i = 0; i < 96; i++) s += deg[base + i];
  part[t] = s;
  __syncthreads();
  for (int off = 1; off < 256; off <<= 1){
    int xv = (t >= off) ? part[t - off] : 0;
    __syncthreads();
    part[t] += xv;
    __syncthreads();
  }
  int run = part[t] - s;
  for (int i = 0; i < 96; i++){
    rowptr[base + i] = run; cursor[base + i] = run; run += deg[base + i];
  }
  if (t == 255) rowptr[NTOT] = run;
}
__global__ void scatter_kernel(const int* __restrict__ ei, int E, int* cursor, int* __restrict__ csr){
  int i = blockIdx.x*256 + threadIdx.x;
  if (i >= E + NTOT) return;
  int s, d;
  if (i < E){ s = ei[i]; d = ei[E + i]; } else { s = i - E; d = s; }
  int pos = atomicAdd(&cursor[d], 1);
  csr[pos] = s;
}

// ---------------- GAT: xh = x@W (NT,256), al_s/al_d per head ----------------
__global__ __launch_bounds__(256) void xh_kernel(const float* __restrict__ feat,
    const float* __restrict__ W, const float* __restrict__ asrc, const float* __restrict__ adst,
    float* __restrict__ xh, float* __restrict__ al){
  __shared__ float sW[64*128];
  __shared__ float sas[256], sad[256];
  int t = threadIdx.x;
  if (t < 256){ sas[t] = asrc[t]; sad[t] = adst[t]; }
  int n = blockIdx.x*256 + t;
  float4 fv[16];
  const float4* fp = (const float4*)(feat + (size_t)n*64);
  #pragma unroll
  for (int i = 0; i < 16; i++) fv[i] = fp[i];
  float4* xp = (float4*)(xh + (size_t)n*256);
  float* ap = al + (size_t)n*8;
  #pragma unroll 1
  for (int half = 0; half < 2; half++){
    __syncthreads();
    for (int i = t; i < 8192; i += 256){
      int d = i >> 7, c = i & 127;
      sW[i] = W[d*256 + half*128 + c];
    }
    __syncthreads();
    #pragma unroll 1
    for (int hh = 0; hh < 2; hh++){
      int h = half*2 + hh;
      float as_ = 0.f, ad_ = 0.f;
      #pragma unroll 1
      for (int cc = 0; cc < 64; cc += 4){
        int c  = h*64 + cc;
        int cl = hh*64 + cc;
        float a0=0,a1=0,a2=0,a3=0;
        #pragma unroll
        for (int d4 = 0; d4 < 16; d4++){
          float4 fq = fv[d4];
          #pragma unroll
          for (int dd = 0; dd < 4; dd++){
            int d = d4*4 + dd;
            float fd = dd==0?fq.x : dd==1?fq.y : dd==2?fq.z : fq.w;
            float4 wv = *(const float4*)&sW[d*128 + cl];
            a0=fmaf(fd,wv.x,a0); a1=fmaf(fd,wv.y,a1); a2=fmaf(fd,wv.z,a2); a3=fmaf(fd,wv.w,a3);
          }
        }
        float4 o; o.x=a0; o.y=a1; o.z=a2; o.w=a3;
        xp[c >> 2] = o;
        as_ = fmaf(a0, sas[c], fmaf(a1, sas[c+1], fmaf(a2, sas[c+2], fmaf(a3, sas[c+3], as_))));
        ad_ = fmaf(a0, sad[c], fmaf(a1, sad[c+1], fmaf(a2, sad[c+2], fmaf(a3, sad[c+3], ad_))));
      }
      ap[h] = as_; ap[4 + h] = ad_;
    }
  }
}

// ---------------- GAT aggregation: one-pass online softmax, one wave per dst ----------------
__global__ __launch_bounds__(256) void agg_kernel(const float* __restrict__ xh, const float* __restrict__ al,
    const int* __restrict__ rowptr, const int* __restrict__ csr,
    const float* __restrict__ resid, const float* __restrict__ bias,
    float* __restrict__ out){
  int gid = blockIdx.x*256 + threadIdx.x;
  int n = gid >> 6, lane = gid & 63;
  int rs = rowptr[n], re = rowptr[n+1];
  int h = lane >> 4, coff = (lane & 15)*4;
  float ald_h = al[(size_t)n*8 + 4 + h];
  float mx = -3.4e38f, den = 0.f;
  float ax=0.f, ay=0.f, az=0.f, aw=0.f;
  #pragma unroll 2
  for (int e = rs; e < re; e++){
    int s = csr[e];
    float a = al[(size_t)s*8 + h] + ald_h;
    a = a > 0.f ? a : 0.2f*a;                   // leaky_relu
    float nm = fmaxf(mx, a);
    float corr = __expf(mx - nm);
    float ea   = __expf(a - nm);
    mx = nm;
    float4 xv = *(const float4*)(xh + (size_t)s*256 + h*64 + coff);
    den = fmaf(den, corr, ea);
    ax = fmaf(ax, corr, ea*xv.x); ay = fmaf(ay, corr, ea*xv.y);
    az = fmaf(az, corr, ea*xv.z); aw = fmaf(aw, corr, ea*xv.w);
  }
  float rinv = 1.f / (den + 1e-16f);
  float r0 = ax*rinv, r1 = ay*rinv, r2 = az*rinv, r3 = aw*rinv;
  r0 += __shfl_xor(r0, 16, 64); r1 += __shfl_xor(r1, 16, 64);
  r2 += __shfl_xor(r2, 16, 64); r3 += __shfl_xor(r3, 16, 64);
  r0 += __shfl_xor(r0, 32, 64); r1 += __shfl_xor(r1, 32, 64);
  r2 += __shfl_xor(r2, 32, 64); r3 += __shfl_xor(r3, 32, 64);
  if (lane < 16){
    float4 bs = *(const float4*)(bias + coff);
    float4 rv = *(const float4*)(resid + (size_t)n*64 + coff);
    float4 o;
    o.x = r0*0.25f + bs.x + rv.x; o.y = r1*0.25f + bs.y + rv.y;
    o.z = r2*0.25f + bs.z + rv.z; o.w = r3*0.25f + bs.w + rv.w;
    *(float4*)(out + (size_t)n*64 + coff) = o;
  }
}

// ---------------- output MLP: 64->64 elu ->32 elu ->8 ----------------
__global__ __launch_bounds__(256) void mlp_kernel(const float* __restrict__ feat,
    const float* __restrict__ W1, const float* __restrict__ b1,
    const float* __restrict__ W2, const float* __restrict__ b2,
    const float* __restrict__ W3, const float* __restrict__ b3,
    float* __restrict__ out){
  __shared__ float s1[4096], s2[2048], s3[256], t1[64], t2[32], t3[8];
  int t = threadIdx.x;
  for (int i = t; i < 4096; i += 256) s1[i] = W1[i];
  for (int i = t; i < 2048; i += 256) s2[i] = W2[i];
  if (t < 256) s3[t] = W3[t];
  if (t < 64) t1[t] = b1[t];
  if (t < 32) t2[t] = b2[t];
  if (t < 8)  t3[t] = b3[t];
  __syncthreads();
  int n = blockIdx.x*256 + t;
  float4 fv[16];
  const float4* fp = (const float4*)(feat + (size_t)n*64);
  #pragma unroll
  for (int i = 0; i < 16; i++) fv[i] = fp[i];
  float o1[64];
  #pragma unroll 1
  for (int c4 = 0; c4 < 16; c4++){
    float a0=t1[c4*4+0], a1=t1[c4*4+1], a2=t1[c4*4+2], a3=t1[c4*4+3];
    #pragma unroll
    for (int d4 = 0; d4 < 16; d4++){
      float4 fq = fv[d4];
      #pragma unroll
      for (int dd = 0; dd < 4; dd++){
        int d = d4*4 + dd;
        float fd = dd==0?fq.x : dd==1?fq.y : dd==2?fq.z : fq.w;
        float4 wv = *(const float4*)&s1[d*64 + c4*4];
        a0=fmaf(fd,wv.x,a0); a1=fmaf(fd,wv.y,a1); a2=fmaf(fd,wv.z,a2); a3=fmaf(fd,wv.w,a3);
      }
    }
    o1[c4*4+0]=elu_f(a0); o1[c4*4+1]=elu_f(a1); o1[c4*4+2]=elu_f(a2); o1[c4*4+3]=elu_f(a3);
  }
  float o2[32];
  #pragma unroll 1
  for (int c4 = 0; c4 < 8; c4++){
    float a0=t2[c4*4+0], a1=t2[c4*4+1], a2=t2[c4*4+2], a3=t2[c4*4+3];
    #pragma unroll
    for (int d = 0; d < 64; d++){
      float fd = o1[d];
      float4 wv = *(const float4*)&s2[d*32 + c4*4];
      a0=fmaf(fd,wv.x,a0); a1=fmaf(fd,wv.y,a1); a2=fmaf(fd,wv.z,a2); a3=fmaf(fd,wv.w,a3);
    }
    o2[c4*4+0]=elu_f(a0); o2[c4*4+1]=elu_f(a1); o2[c4*4+2]=elu_f(a2); o2[c4*4+3]=elu_f(a3);
  }
  float4* op = (float4*)(out + (size_t)n*8);
  #pragma unroll
  for (int c4 = 0; c4 < 2; c4++){
    float a0=t3[c4*4+0], a1=t3[c4*4+1], a2=t3[c4*4+2], a3=t3[c4*4+3];
    #pragma unroll
    for (int d = 0; d < 32; d++){
      float fd = o2[d];
      float4 wv = *(const float4*)&s3[d*8 + c4*4];
      a0=fmaf(fd,wv.x,a0); a1=fmaf(fd,wv.y,a1); a2=fmaf(fd,wv.z,a2); a3=fmaf(fd,wv.w,a3);
    }
    float4 o; o.x=a0; o.y=a1; o.z=a2; o.w=a3;
    op[c4] = o;
  }
}

extern "C" void kernel_launch(void* const* d_in, const int* in_sizes, int n_in,
                              void* d_out, int out_size, void* d_ws, size_t ws_size,
                              hipStream_t stream){
  (void)n_in; (void)out_size; (void)ws_size;
  const float* x     = (const float*)d_in[0];
  const int*   ei    = (const int*)d_in[2];
  const int    E     = in_sizes[2] / 2;
  const float* encW1 = (const float*)d_in[3];
  const float* encb1 = (const float*)d_in[4];
  const float* encW2 = (const float*)d_in[5];
  const float* encb2 = (const float*)d_in[6];
  const float* convW = (const float*)d_in[7];
  const float* convb = (const float*)d_in[8];
  const float* bng   = (const float*)d_in[9];
  const float* bnb   = (const float*)d_in[10];
  const float* bnm   = (const float*)d_in[11];
  const float* bnv   = (const float*)d_in[12];
  const float* gatW  = (const float*)d_in[13];
  const float* gatas = (const float*)d_in[14];
  const float* gatad = (const float*)d_in[15];
  const float* gatb  = (const float*)d_in[16];
  const float* oW1   = (const float*)d_in[17];
  const float* ob1   = (const float*)d_in[18];
  const float* oW2   = (const float*)d_in[19];
  const float* ob2   = (const float*)d_in[20];
  const float* oW3   = (const float*)d_in[21];
  const float* ob3   = (const float*)d_in[22];

  char* wp = (char*)d_ws;
  auto alloc = [&](size_t bytes)->void*{
    void* p = (void*)wp; wp += (bytes + 255) & ~((size_t)255); return p;
  };
  float* fA     = (float*)alloc((size_t)NTOT*64*4);
  float* fB     = (float*)alloc((size_t)NTOT*64*4);
  float* ubuf   = (float*)alloc((size_t)NTOT*64*4);
  float* vbuf   = (float*)alloc((size_t)NTOT*64*4);
  float* sqb    = (float*)alloc((size_t)NTOT*4);
  int*   idxb   = (int*)  alloc((size_t)NTOT*KNN*4);
  float* xhb    = (float*)alloc((size_t)NTOT*256*4);
  float* alb    = (float*)alloc((size_t)NTOT*8*4);
  int*   degb   = (int*)  alloc((size_t)NTOT*4);
  int*   rowptr = (int*)  alloc((size_t)(NTOT+1)*4);
  int*   cursor = (int*)  alloc((size_t)NTOT*4);
  int*   csr    = (int*)  alloc((size_t)(E+NTOT)*4);
  float* topv   = (float*)alloc((size_t)NTOT*288*4);
  unsigned int* topi = (unsigned int*)alloc((size_t)NTOT*96*4);

  enc_kernel<<<96,256,0,stream>>>(x, encW1, encb1, encW2, encb2, fA, sqb);
  float* cur = fA; float* nxt = fB;
  for (int l = 0; l < 3; l++){
    disttop_kernel<<<dim3(TPAIRS,1,NB),256,0,stream>>>(cur, sqb, topv, topi);
    ksel_kernel   <<<NTOT/4,              256,0,stream>>>(topv, topi, cur, sqb, idxb);
    uv_kernel  <<<96,  256,0,stream>>>(cur, convW + (size_t)l*8192, convb + l*64, ubuf, vbuf);
    pool_kernel<<<6144,256,0,stream>>>(ubuf, vbuf, idxb, cur,
                                       bng + l*64, bnb + l*64, bnm + l*64, bnv + l*64, nxt, sqb);
    float* tmp = cur; cur = nxt; nxt = tmp;
  }
  deg_init   <<<96,            256,0,stream>>>(degb);
  deg_hist   <<<(E+255)/256,   256,0,stream>>>(ei, E, degb);
  scan_kernel<<<1,             256,0,stream>>>(degb, rowptr, cursor);
  scatter_kernel<<<(E+NTOT+255)/256,256,0,stream>>>(ei, E, cursor, csr);
  for (int l = 0; l < 2; l++){
    xh_kernel <<<96,  256,0,stream>>>(cur, gatW + (size_t)l*16384, gatas + l*256, gatad + l*256, xhb, alb);
    agg_kernel<<<6144,256,0,stream>>>(xhb, alb, rowptr, csr, cur, gatb + l*64, nxt);
    float* tmp = cur; cur = nxt; nxt = tmp;
  }
  mlp_kernel<<<96,256,0,stream>>>(cur, oW1, ob1, oW2, ob2, oW3, ob3, (float*)d_out);
}